// Round 7
// baseline (375.405 us; speedup 1.0000x reference)
//
#include <hip/hip_runtime.h>

typedef unsigned long long u64;
typedef unsigned short ushort_t;

#define NA 50000
#define NE 400000
#define DF 128
#define HID 64
#define NMOL 256
#define NOUT 32
#define NSTEP 3
#define NPB 782  // node_proj blocks: ceil(NA/64)

// ---- atomic-free sort geometry ----
#define RNG 8192          // dst bins per range slice
#define NRNG 7            // ceil(NA/RNG)
#define NCH 32            // edge chunks (32: halves H/Orel traffic vs 64)
#define CHUNK 12500       // NE/NCH (< 65536 so u16 histograms stay valid)
#define NCHM 16           // mol chunks
#define CHM 3125          // NA/NCHM
#define NWB 336           // weight-pack blocks: 86016/256
#define HISTB (NRNG*NCH + NCHM + NWB)   // 576
#define SCATB (NRNG*NCH + NCHM)         // 240
#define MBUF_ROWS 110000  // 8-edge windows: R <= NE/8 + NA = 100000 (+margin)

// ---- persistent edge_msg geometry ----
#define NT (NE / 16)      // 25000 tiles of 16 edges
#define EBLK 1024         // persistent blocks
#define EGW (EBLK * 4)    // 4096 grid waves

typedef __attribute__((ext_vector_type(8))) unsigned short ushort8;
typedef __attribute__((ext_vector_type(4))) float f32x4;
typedef __attribute__((ext_vector_type(8))) _Float16 half8;
typedef __attribute__((ext_vector_type(2))) _Float16 half2_t;
typedef __attribute__((ext_vector_type(2))) __fp16 fp16x2;

static __device__ __forceinline__ ushort_t f2h(float f) {
  union { _Float16 h; ushort_t u; } v; v.h = (_Float16)f; return v.u;
}
static __device__ __forceinline__ float hlo(unsigned d) {
  union { unsigned u; half2_t h; } v; v.u = d; return (float)v.h[0];
}
static __device__ __forceinline__ float hhi(unsigned d) {
  union { unsigned u; half2_t h; } v; v.u = d; return (float)v.h[1];
}
static __device__ __forceinline__ unsigned pkrtz(float a, float b) {
  union { fp16x2 h; unsigned u; } v;
  v.h = __builtin_amdgcn_cvt_pkrtz(a, b);
  return v.u;
}

// ---- hist_all: dst-range histograms + mol histograms + weight pack --------
__global__ __launch_bounds__(256) void hist_all(
    const int* __restrict__ dst, const int* __restrict__ mol_ids,
    const float* __restrict__ Win, const float* __restrict__ Wh,
    const float* __restrict__ Wout,
    ushort_t* __restrict__ WpB, ushort_t* __restrict__ WhB,
    ushort_t* __restrict__ WoB,
    ushort_t* __restrict__ H, unsigned* __restrict__ MH,
    int* __restrict__ mcnt) {
  __shared__ unsigned hist[RNG];
  const int b = blockIdx.x, t = threadIdx.x;
  if (b < NRNG * NCH) {
    const int r = b / NCH, c = b % NCH;
    const int lo = r * RNG;
    for (int i = t; i < RNG; i += 256) hist[i] = 0;
    __syncthreads();
    const int base = c * CHUNK;
    for (int k = t; k < CHUNK; k += 256) {
      int d = dst[base + k];
      unsigned rel = (unsigned)(d - lo);
      if (rel < RNG) atomicAdd(&hist[rel], 1u);
    }
    __syncthreads();
    ushort_t* Hp = H + (u64)b * RNG;
    for (int i = t; i < RNG; i += 256) Hp[i] = (ushort_t)hist[i];
    return;
  }
  int b2 = b - NRNG * NCH;
  if (b2 < NCHM) {
    if (t < 256) hist[t] = 0;
    __syncthreads();
    const int base = b2 * CHM;
    for (int k = t; k < CHM; k += 256) atomicAdd(&hist[mol_ids[base + k]], 1u);
    __syncthreads();
    if (t < 256) {
      MH[b2 * 256 + t] = hist[t];
      if (hist[t]) atomicAdd(&mcnt[t], (int)hist[t]);
    }
    return;
  }
  // ---- weight pack (fp16 B-frag order) ----
  int g = (b2 - NCHM) * 256 + t;
  if (g < 3 * 16384) {
    int tt = g / 16384, r = g % 16384;
    int j = r & 7, lane = (r >> 3) & 63, f = r >> 9;
    int kc = f & 3, nt = f >> 2;
    int k = kc * 32 + (lane >> 4) * 8 + j;
    int n = nt * 16 + (lane & 15);
    float v = (n < 64) ? Win[tt * 16384 + k * 64 + n]
                       : Win[tt * 16384 + (128 + k) * 64 + (n - 64)];
    WpB[g] = f2h(v);
  }
  int g2 = g - 3 * 16384;
  if (g2 >= 0 && g2 < 3 * 4096) {
    int tt = g2 / 4096, r = g2 % 4096;
    int j = r & 7, lane = (r >> 3) & 63, f = r >> 9;
    int kc = f & 1, nt = f >> 1;
    int k = kc * 32 + (lane >> 4) * 8 + j;
    int n = nt * 16 + (lane & 15);
    WhB[g2] = f2h(Wh[tt * 4096 + k * 64 + n]);
  }
  int g3 = g2 - 3 * 4096;
  if (g3 >= 0 && g3 < 3 * 8192) {
    int tt = g3 / 8192, r = g3 % 8192;
    int j = r & 7, lane = (r >> 3) & 63, f = r >> 9;
    int kc = f & 1, nt = f >> 1;
    int k = kc * 32 + (lane >> 4) * 8 + j;
    int n = nt * 16 + (lane & 15);
    WoB[g3] = f2h(Wout[tt * 8192 + k * 128 + n]);
  }
}

// ---- col_scan: per-bin prefix over chunks -> Orel[c][bin], counts[bin] ----
__global__ void col_scan(const ushort_t* __restrict__ H,
                         ushort_t* __restrict__ Orel, int* __restrict__ counts) {
  int bidx = blockIdx.x * 256 + threadIdx.x;
  if (bidx >= NA) return;
  int r = bidx >> 13, i = bidx & (RNG - 1);
  const ushort_t* Hp = H + ((u64)r * NCH) * RNG + i;
  unsigned acc = 0;
  for (int c = 0; c < NCH; c++) {
    Orel[(u64)c * NA + bidx] = (ushort_t)acc;
    acc += Hp[(u64)c * RNG];
  }
  counts[bidx] = (int)acc;
}

// per-1024-block inclusive scan of counts; last block also scans mol histogram
__global__ void scan_phase1(const int* __restrict__ counts, int* __restrict__ tmp,
                            int* __restrict__ blk,
                            const int* __restrict__ mcnt, int* __restrict__ mrow) {
  __shared__ int sh[1024];
  int t = threadIdx.x;
  int i = blockIdx.x * 1024 + t;
  sh[t] = (i < NA) ? counts[i] : 0;
  __syncthreads();
  for (int off = 1; off < 1024; off <<= 1) {
    int x = (t >= off) ? sh[t - off] : 0;
    __syncthreads();
    sh[t] += x;
    __syncthreads();
  }
  if (i < NA) tmp[i] = sh[t];
  if (t == 1023) blk[blockIdx.x] = sh[1023];
  if (blockIdx.x == gridDim.x - 1) {  // fold in the molecule scan
    __syncthreads();
    sh[t] = (t < NMOL) ? mcnt[t] : 0;
    __syncthreads();
    for (int off = 1; off < NMOL; off <<= 1) {
      int x = (t >= off && t < NMOL) ? sh[t - off] : 0;
      __syncthreads();
      if (t < NMOL) sh[t] += x;
      __syncthreads();
    }
    if (t < NMOL) mrow[t + 1] = sh[t];
    if (t == 0) mrow[0] = 0;
  }
}

// row_ptr[i+1] = tmp[i] + prefix(blk); ALSO block-scan of per-dst window counts
// 8-edge windows: nwin(d) = ((re-1)>>3) - (rs>>3) + 1
__global__ void scan_phase3(const int* __restrict__ tmp, const int* __restrict__ blk,
                            int* __restrict__ row_ptr,
                            int* __restrict__ ntmp, int* __restrict__ nblk) {
  __shared__ int sh[1024];
  __shared__ int spre_sh;
  int t = threadIdx.x;
  int bid = blockIdx.x;
  if (t < 64) {
    int v = (t < bid) ? blk[t] : 0;  // bid <= 48 < 64
    for (int off = 32; off; off >>= 1) v += __shfl_down(v, off);
    if (t == 0) spre_sh = v;
  }
  __syncthreads();
  int spre = spre_sh;
  int i = bid * 1024 + t;
  int nwin = 0;
  if (i < NA) {
    int re = tmp[i] + spre;                           // row_ptr[i+1]
    int rs = (t == 0) ? spre : (tmp[i - 1] + spre);   // row_ptr[i]
    row_ptr[i + 1] = re;
    if (re > rs) nwin = ((re - 1) >> 3) - (rs >> 3) + 1;
  }
  if (i == 0) row_ptr[0] = 0;
  sh[t] = nwin;
  __syncthreads();
  for (int off = 1; off < 1024; off <<= 1) {
    int x = (t >= off) ? sh[t - off] : 0;
    __syncthreads();
    sh[t] += x;
    __syncthreads();
  }
  if (i < NA) ntmp[i] = sh[t];
  if (t == 1023) nblk[bid] = sh[1023];
}

// orow[i] = sub-run prefix; orow2[d] = orow[d] - (row_ptr[d]>>3)
__global__ void nscan_p3(const int* __restrict__ ntmp, const int* __restrict__ nblk,
                         const int* __restrict__ row_ptr,
                         int* __restrict__ orow, int* __restrict__ orow2) {
  __shared__ int spre_sh;
  int t = threadIdx.x;
  int bid = blockIdx.x;
  if (t < 64) {
    int v = (t < bid) ? nblk[t] : 0;  // bid <= 48 < 64
    for (int off = 32; off; off >>= 1) v += __shfl_down(v, off);
    if (t == 0) spre_sh = v;
  }
  __syncthreads();
  int spre = spre_sh;
  int i = bid * 1024 + t;
  if (i < NA) {
    orow[i + 1] = ntmp[i] + spre;
    int oi = (t == 0) ? spre : (ntmp[i - 1] + spre);  // orow[i]
    orow2[i] = oi - (row_ptr[i] >> 3);
  }
  if (i == 0) orow[0] = 0;
}

// ---- scat_all: atomic-free scatter via LDS ranks + offset table -----------
__global__ __launch_bounds__(256) void scat_all(
    const int* __restrict__ dst, const int* __restrict__ src,
    const int* __restrict__ row_ptr, const ushort_t* __restrict__ Orel,
    unsigned* __restrict__ ds_pack,
    const int* __restrict__ mol_ids, const int* __restrict__ mrow,
    const unsigned* __restrict__ MH, int* __restrict__ mol_sorted) {
  __shared__ unsigned cnt[RNG];
  __shared__ unsigned mbase[256];
  const int b = blockIdx.x, t = threadIdx.x;
  if (b < NRNG * NCH) {
    const int r = b / NCH, c = b % NCH;
    const int lo = r * RNG;
    for (int i = t; i < RNG; i += 256) cnt[i] = 0;
    __syncthreads();
    const int base = c * CHUNK;
    const ushort_t* Op = Orel + (u64)c * NA;
    for (int k = t; k < CHUNK; k += 256) {
      int e = base + k;
      int d = dst[e];
      unsigned rel = (unsigned)(d - lo);
      if (rel < RNG) {
        unsigned lr = atomicAdd(&cnt[rel], 1u);
        int pos = row_ptr[d] + (int)Op[d] + (int)lr;
        ds_pack[pos] = ((unsigned)d << 16) | (unsigned)src[e];
      }
    }
    return;
  }
  const int c2 = b - NRNG * NCH;  // mol chunk
  if (t < 256) {
    unsigned s = (unsigned)mrow[t];
    for (int cp = 0; cp < c2; cp++) s += MH[cp * 256 + t];
    mbase[t] = s;
    cnt[t] = 0;
  }
  __syncthreads();
  const int base = c2 * CHM;
  for (int k = t; k < CHM; k += 256) {
    int a = base + k;
    int m = mol_ids[a];
    unsigned lr = atomicAdd(&cnt[m], 1u);
    mol_sorted[mbase[m] + lr] = a;
  }
}

// -------- node projection (step 0): states f32 -> PQb fp16 -----------------
__global__ __launch_bounds__(256) void node_proj(
    const float* __restrict__ s_in, const ushort_t* __restrict__ WpB,
    const float* __restrict__ b_in, ushort_t* __restrict__ PQb) {
  const int t = threadIdx.x;
  const int lane = t & 63, wv = t >> 6, quad = lane >> 4, l15 = lane & 15;
  const int n0 = blockIdx.x * 64 + wv * 16;
  int n = n0 + l15; if (n >= NA) n = NA - 1;
  union { half8 v; unsigned d[4]; } a[4];
#pragma unroll
  for (int c = 0; c < 4; c++) {
    const float* p = s_in + (u64)n * 128 + c * 32 + quad * 8;
    float4 f0 = *(const float4*)(p);
    float4 f1 = *(const float4*)(p + 4);
    a[c].d[0] = pkrtz(f0.x, f0.y);
    a[c].d[1] = pkrtz(f0.z, f0.w);
    a[c].d[2] = pkrtz(f1.x, f1.y);
    a[c].d[3] = pkrtz(f1.z, f1.w);
  }
  float binv[4];
#pragma unroll
  for (int nt = 0; nt < 4; nt++) binv[nt] = b_in[nt * 16 + l15];
#pragma unroll
  for (int nt = 0; nt < 8; nt++) {
    f32x4 acc = {0.f, 0.f, 0.f, 0.f};
#pragma unroll
    for (int c = 0; c < 4; c++) {
      half8 b = *(const half8*)&WpB[((nt * 4 + c) * 64 + lane) * 8];
      acc = __builtin_amdgcn_mfma_f32_16x16x32_f16(a[c].v, b, acc, 0, 0, 0);
    }
    float bias = (nt < 4) ? binv[nt] : 0.f;
#pragma unroll
    for (int r = 0; r < 4; r++) {
      int nn = n0 + quad * 4 + r;
      if (nn < NA) PQb[(u64)nn * 128 + nt * 16 + l15] = f2h(acc[r] + bias);
    }
  }
}

// ------ persistent fused edge MLP (fp16 MFMA) -> packed-fp16 sub-run sums --
// 8-edge sub-run windows: quads pair (0,1),(2,3); connecting run merged via
// one shfl_xor(16) of the odd quad's fp16-packed head sum.
__global__ __launch_bounds__(256) void edge_msg(
    const ushort_t* __restrict__ PQb,
    const ushort_t* __restrict__ WhB, const ushort_t* __restrict__ WoB,
    const float* __restrict__ b_h, const float* __restrict__ b_out,
    const unsigned* __restrict__ ds_pack, const int* __restrict__ orow2,
    unsigned* __restrict__ m_buf) {
  __shared__ ushort_t h2s[4][16 * 72];  // per-wave 16 x 64 fp16 repack tile
  const int t = threadIdx.x;
  const int lane = t & 63, wv = t >> 6, quad = lane >> 4, l15 = lane & 15;
  const int gw = blockIdx.x * 4 + wv;   // global wave id in [0, EGW)

  float bh[4], bo[8];
#pragma unroll
  for (int nt = 0; nt < 4; nt++) bh[nt] = b_h[nt * 16 + l15];
#pragma unroll
  for (int nt = 0; nt < 8; nt++) bo[nt] = b_out[nt * 16 + l15];

  ushort_t* hb = h2s[wv];
  const int colq = quad * 8;
  const half2_t z2 = {(_Float16)0.f, (_Float16)0.f};

  struct Ctx {
    int e;            // this lane's edge index (tile*16 + l15)
    unsigned pk;      // (dst<<16)|src
    int o;            // sub-run row of edge e (8-window)
    ushort8 pv0, pv1, qv0, qv1;
  };

  auto load_pk = [&](Ctx& c, int tile) {
    c.e = tile * 16 + l15;
    c.pk = ds_pack[c.e];
  };
  auto gather = [&](Ctx& c) {
    u64 da = c.pk >> 16, sa = c.pk & 0xffffu;
    c.o = orow2[da] + (c.e >> 3);
    c.pv0 = *(const ushort8*)&PQb[da * 128 + colq];
    c.pv1 = *(const ushort8*)&PQb[da * 128 + 32 + colq];
    c.qv0 = *(const ushort8*)&PQb[sa * 128 + 64 + colq];
    c.qv1 = *(const ushort8*)&PQb[sa * 128 + 96 + colq];
  };
  auto compute = [&](Ctx& c) {
    union UPQ { ushort8 u; half2_t h[4]; };
    UPQ P0, P1, Q0, Q1;
    P0.u = c.pv0; P1.u = c.pv1; Q0.u = c.qv0; Q1.u = c.qv1;
    union { half8 v; half2_t h[4]; } a1[2];
#pragma unroll
    for (int k = 0; k < 4; k++) {
      half2_t s0 = P0.h[k] + Q0.h[k];
      half2_t s1 = P1.h[k] + Q1.h[k];
      a1[0].h[k] = __builtin_elementwise_max(s0, z2);
      a1[1].h[k] = __builtin_elementwise_max(s1, z2);
    }
    // h2 = relu(h1 @ Wh + b_h) -> wave-private LDS repack
#pragma unroll
    for (int nt = 0; nt < 4; nt++) {
      f32x4 acc = {0.f, 0.f, 0.f, 0.f};
#pragma unroll
      for (int cc = 0; cc < 2; cc++) {
        half8 b = *(const half8*)&WhB[((nt * 2 + cc) * 64 + lane) * 8];
        acc = __builtin_amdgcn_mfma_f32_16x16x32_f16(a1[cc].v, b, acc, 0, 0, 0);
      }
#pragma unroll
      for (int r = 0; r < 4; r++)
        hb[(quad * 4 + r) * 72 + nt * 16 + l15] =
            f2h(fmaxf(acc[r] + bh[nt], 0.f));
    }
    half8 a2[2];
    a2[0] = *(const half8*)&hb[l15 * 72 + colq];
    a2[1] = *(const half8*)&hb[l15 * 72 + 32 + colq];
    // m = relu(h2 @ Wout + b_out)
    f32x4 acc2[8];
#pragma unroll
    for (int nt = 0; nt < 8; nt++) {
      f32x4 acc = {0.f, 0.f, 0.f, 0.f};
#pragma unroll
      for (int cc = 0; cc < 2; cc++) {
        half8 b = *(const half8*)&WoB[((nt * 2 + cc) * 64 + lane) * 8];
        acc = __builtin_amdgcn_mfma_f32_16x16x32_f16(a2[cc], b, acc, 0, 0, 0);
      }
      acc2[nt] = acc;
    }
    // ---- segmented 8-window flush with cross-quad (pair) merge ----
    // window = 8 aligned edges; quad q owns edges q*4..q*4+3 of the tile.
    const int grp = lane & 48;
    const int wb = (quad & 2) * 4;        // window base within tile: 0 or 8
    const bool odd = (quad & 1) != 0;
    const int jb = odd ? 4 : 0;           // my sub-range start within window
    int pkd[8];
#pragma unroll
    for (int r = 0; r < 8; r++) pkd[r] = __shfl((int)c.pk, grp + wb + r);
    int orr[4];
#pragma unroll
    for (int r = 0; r < 4; r++) orr[r] = __shfl(c.o, grp + quad * 4 + r);
    const bool conn =
        ((((unsigned)pkd[3]) >> 16) == (((unsigned)pkd[4]) >> 16));
    unsigned dpre = ((unsigned)pkd[jb]) >> 16;
    int cur_row = orr[0];
    float run[8];
    unsigned sx[4];
    bool head_done = false;
#pragma unroll
    for (int nt = 0; nt < 8; nt++) run[nt] = 0.f;
#pragma unroll
    for (int k = 0; k < 4; k++) sx[k] = 0u;
#pragma unroll
    for (int r = 0; r < 4; r++) {
      unsigned dcur = ((unsigned)pkd[jb + r]) >> 16;
      if (dcur != dpre) {
        unsigned w[4];
#pragma unroll
        for (int k = 0; k < 4; k++) w[k] = pkrtz(run[2 * k], run[2 * k + 1]);
        if (!head_done) {
          head_done = true;
#pragma unroll
          for (int k = 0; k < 4; k++) sx[k] = w[k];
          if (!(odd && conn)) {
            unsigned* rowp = m_buf + (u64)cur_row * 64;
#pragma unroll
            for (int k = 0; k < 4; k++) rowp[k * 16 + l15] = w[k];
          }
        } else {
          unsigned* rowp = m_buf + (u64)cur_row * 64;
#pragma unroll
          for (int k = 0; k < 4; k++) rowp[k * 16 + l15] = w[k];
        }
#pragma unroll
        for (int nt = 0; nt < 8; nt++) run[nt] = 0.f;
        dpre = dcur; cur_row = orr[r];
      }
#pragma unroll
      for (int nt = 0; nt < 8; nt++)
        run[nt] += fmaxf(acc2[nt][r] + bo[nt], 0.f);
    }
    // exchange head (or whole-quad sum if uniform) with partner quad
    if (!head_done) {
#pragma unroll
      for (int k = 0; k < 4; k++) sx[k] = pkrtz(run[2 * k], run[2 * k + 1]);
    }
    unsigned rx[4];
#pragma unroll
    for (int k = 0; k < 4; k++)
      rx[k] = (unsigned)__shfl_xor((int)sx[k], 16);
    if (!odd) {
      if (conn) {
#pragma unroll
        for (int k = 0; k < 4; k++) {
          run[2 * k] += hlo(rx[k]);
          run[2 * k + 1] += hhi(rx[k]);
        }
      }
      unsigned* rowp = m_buf + (u64)cur_row * 64;
#pragma unroll
      for (int k = 0; k < 4; k++)
        rowp[k * 16 + l15] = pkrtz(run[2 * k], run[2 * k + 1]);
    } else {
      if (!(conn && !head_done)) {
        unsigned* rowp = m_buf + (u64)cur_row * 64;
#pragma unroll
        for (int k = 0; k < 4; k++)
          rowp[k * 16 + l15] = pkrtz(run[2 * k], run[2 * k + 1]);
      }
    }
  };

  // ---- 3-stage pipelined grid-stride loop ----
  Ctx A, B, C;
  int tc = gw;                 // gw < EGW <= NT always
  load_pk(A, tc);
  int tb = tc + EGW;
  if (tb < NT) load_pk(B, tb);
  gather(A);
  while (tc < NT) {
    int tn = tc + EGW;
    if (tn < NT) gather(B);
    int t2 = tn + EGW;
    if (t2 < NT) load_pk(C, t2);
    compute(A);
    A = B; B = C;
    tc = tn;
  }
}

// ---- fused dst aggregation + projection; bounds staged in LDS -------------
__global__ __launch_bounds__(256) void agg_proj(
    const unsigned* __restrict__ m_buf, const int* __restrict__ orow,
    const ushort_t* __restrict__ WpB, const float* __restrict__ b_in,
    ushort_t* __restrict__ PQb) {
  __shared__ ushort_t a_s[64 * 136];  // 64 rows x 128 fp16, pitch 136
  __shared__ int obs_s[65];
  const int t = threadIdx.x;
  const int lane = t & 63, wv = t >> 6, quad = lane >> 4, l15 = lane & 15;
  const int n0 = blockIdx.x * 64;
  if (t < 65) {
    int idx = n0 + t; if (idx > NA) idx = NA;
    obs_s[t] = orow[idx];
  }
  __syncthreads();

  for (int r = 0; r < 16; r++) {
    const int d = n0 + wv * 16 + r;
    float s0 = 0.f, s1 = 0.f;
    if (d < NA) {
      int ob = obs_s[wv * 16 + r], oe = obs_s[wv * 16 + r + 1];
      int n = oe - ob;
      float t0 = 0.f, t1 = 0.f, u0 = 0.f, u1 = 0.f, v0 = 0.f, v1 = 0.f;
      int full = n & ~3;
      int e = ob;
      for (; e < ob + full; e += 4) {
        unsigned w0 = m_buf[(u64)(e + 0) * 64 + lane];
        unsigned w1 = m_buf[(u64)(e + 1) * 64 + lane];
        unsigned w2 = m_buf[(u64)(e + 2) * 64 + lane];
        unsigned w3 = m_buf[(u64)(e + 3) * 64 + lane];
        s0 += hlo(w0); s1 += hhi(w0);
        t0 += hlo(w1); t1 += hhi(w1);
        u0 += hlo(w2); u1 += hhi(w2);
        v0 += hlo(w3); v1 += hhi(w3);
      }
      int rem = n - full;
      if (rem > 0) {
        int i1 = (rem > 1) ? e + 1 : e;
        int i2 = (rem > 2) ? e + 2 : e;
        unsigned w0 = m_buf[(u64)e * 64 + lane];
        unsigned w1 = m_buf[(u64)i1 * 64 + lane];
        unsigned w2 = m_buf[(u64)i2 * 64 + lane];
        s0 += hlo(w0); s1 += hhi(w0);
        if (rem > 1) { t0 += hlo(w1); t1 += hhi(w1); }
        if (rem > 2) { u0 += hlo(w2); u1 += hhi(w2); }
      }
      s0 = (s0 + t0) + (u0 + v0);
      s1 = (s1 + t1) + (u1 + v1);
    }
    const int row = wv * 16 + r;
    a_s[row * 136 + quad * 32 + l15] = f2h(s0);
    a_s[row * 136 + quad * 32 + 16 + l15] = f2h(s1);
  }
  // wave-private tile: same-wave LDS RAW ordered by lgkmcnt, no barrier

  float binv[4];
#pragma unroll
  for (int nt = 0; nt < 4; nt++) binv[nt] = b_in[nt * 16 + l15];
  half8 a[4];
#pragma unroll
  for (int c = 0; c < 4; c++)
    a[c] = *(const half8*)&a_s[(wv * 16 + l15) * 136 + c * 32 + quad * 8];
#pragma unroll
  for (int nt = 0; nt < 8; nt++) {
    f32x4 acc = {0.f, 0.f, 0.f, 0.f};
#pragma unroll
    for (int c = 0; c < 4; c++) {
      half8 b = *(const half8*)&WpB[((nt * 4 + c) * 64 + lane) * 8];
      acc = __builtin_amdgcn_mfma_f32_16x16x32_f16(a[c], b, acc, 0, 0, 0);
    }
    float bias = (nt < 4) ? binv[nt] : 0.f;
#pragma unroll
    for (int r = 0; r < 4; r++) {
      int nn = n0 + wv * 16 + quad * 4 + r;
      if (nn < NA) PQb[(u64)nn * 128 + nt * 16 + l15] = f2h(acc[r] + bias);
    }
  }
}

// ---- final aggregation: m_buf sub-runs -> per-mol sums; bounds in LDS -----
__global__ __launch_bounds__(256) void agg_mol2(
    const unsigned* __restrict__ m_buf, const int* __restrict__ orow,
    const int* __restrict__ mol_sorted, const int* __restrict__ mol_ids,
    float* __restrict__ mol_repr) {
  __shared__ int mids[64], obs[64], oes[64];
  const int t = threadIdx.x;
  const int lane = t & 63, wv = t >> 6;
  const int base = blockIdx.x * 64;
  if (t < 64) {
    int idx = base + t;
    int r = (idx < NA) ? mol_sorted[idx] : 0;
    mids[t] = (idx < NA) ? mol_ids[r] : -1;
    obs[t] = orow[r];
    oes[t] = orow[r + 1];
  }
  __syncthreads();
  const int c0 = (lane >> 4) * 32 + (lane & 15);  // unpacked cols c0, c0+16
  float r0 = 0.f, r1 = 0.f;
  int prev = mids[wv * 16];
  for (int i = 0; i < 16; i++) {
    int li = wv * 16 + i;
    int m = mids[li];
    if (m != prev) {
      if (prev >= 0) {
        atomicAdd(&mol_repr[(u64)prev * 128 + c0], r0);
        atomicAdd(&mol_repr[(u64)prev * 128 + c0 + 16], r1);
      }
      r0 = 0.f; r1 = 0.f; prev = m;
    }
    if (m >= 0) {
      int ob = obs[li], oe = oes[li];
      int n = oe - ob;
      float t0 = 0.f, t1 = 0.f, u0 = 0.f, u1 = 0.f, v0 = 0.f, v1 = 0.f;
      int full = n & ~3;
      int e = ob;
      for (; e < ob + full; e += 4) {
        unsigned w0 = m_buf[(u64)(e + 0) * 64 + lane];
        unsigned w1 = m_buf[(u64)(e + 1) * 64 + lane];
        unsigned w2 = m_buf[(u64)(e + 2) * 64 + lane];
        unsigned w3 = m_buf[(u64)(e + 3) * 64 + lane];
        r0 += hlo(w0); r1 += hhi(w0);
        t0 += hlo(w1); t1 += hhi(w1);
        u0 += hlo(w2); u1 += hhi(w2);
        v0 += hlo(w3); v1 += hhi(w3);
      }
      int rem = n - full;
      if (rem > 0) {
        int i1 = (rem > 1) ? e + 1 : e;
        int i2 = (rem > 2) ? e + 2 : e;
        unsigned w0 = m_buf[(u64)e * 64 + lane];
        unsigned w1 = m_buf[(u64)i1 * 64 + lane];
        unsigned w2 = m_buf[(u64)i2 * 64 + lane];
        r0 += hlo(w0); r1 += hhi(w0);
        if (rem > 1) { t0 += hlo(w1); t1 += hhi(w1); }
        if (rem > 2) { u0 += hlo(w2); u1 += hhi(w2); }
      }
      r0 += (t0 + u0) + v0;
      r1 += (t1 + u1) + v1;
    }
  }
  if (prev >= 0) {
    atomicAdd(&mol_repr[(u64)prev * 128 + c0], r0);
    atomicAdd(&mol_repr[(u64)prev * 128 + c0 + 16], r1);
  }
}

// ---------------- final tiny MLP per molecule ----------------
__global__ void final_mlp(const float* __restrict__ mol_repr,
                          const float* __restrict__ fc1_w, const float* __restrict__ fc1_b,
                          const float* __restrict__ fc2_w, const float* __restrict__ fc2_b,
                          const float* __restrict__ out_w, const float* __restrict__ out_b,
                          float* __restrict__ out) {
  int m = blockIdx.x, j = threadIdx.x;
  __shared__ float h1sh[64], h2sh[64];
  const float* mr = mol_repr + (u64)m * DF;
  float acc = fc1_b[j];
  for (int d = 0; d < DF; d++) acc = fmaf(mr[d], fc1_w[d * 64 + j], acc);
  h1sh[j] = fmaxf(acc, 0.f);
  __syncthreads();
  acc = fc2_b[j];
  for (int k = 0; k < 64; k++) acc = fmaf(h1sh[k], fc2_w[k * 64 + j], acc);
  h2sh[j] = fmaxf(acc, 0.f);
  __syncthreads();
  if (j < NOUT) {
    acc = out_b[j];
    for (int k = 0; k < 64; k++) acc = fmaf(h2sh[k], out_w[k * NOUT + j], acc);
    out[(u64)m * NOUT + j] = acc;
  }
}

extern "C" void kernel_launch(void* const* d_in, const int* in_sizes, int n_in,
                              void* d_out, int out_size, void* d_ws, size_t ws_size,
                              hipStream_t stream) {
  const float* states = (const float*)d_in[0];
  const float* Win    = (const float*)d_in[1];
  const float* b_in   = (const float*)d_in[2];
  const float* Wh     = (const float*)d_in[3];
  const float* b_h    = (const float*)d_in[4];
  const float* Wout   = (const float*)d_in[5];
  const float* b_out  = (const float*)d_in[6];
  const float* fc1_w  = (const float*)d_in[7];
  const float* fc1_b  = (const float*)d_in[8];
  const float* fc2_w  = (const float*)d_in[9];
  const float* fc2_b  = (const float*)d_in[10];
  const float* out_w  = (const float*)d_in[11];
  const float* out_b  = (const float*)d_in[12];
  const int* src      = (const int*)d_in[13];
  const int* dst      = (const int*)d_in[14];
  const int* mol_ids  = (const int*)d_in[15];

  char* ws = (char*)d_ws;
  u64 o = 0;
  auto alloc = [&](u64 bytes) {
    void* p = ws + o;
    o += (bytes + 255) & ~255ull;
    return p;
  };
  unsigned* m_buf = (unsigned*)alloc((u64)MBUF_ROWS * 64 * 4);
  ushort_t* PQb  = (ushort_t*)alloc((u64)NA * DF * 2);
  ushort_t* WpB  = (ushort_t*)alloc(3 * 16384 * 2);
  ushort_t* WhB  = (ushort_t*)alloc(3 * 4096 * 2);
  ushort_t* WoB  = (ushort_t*)alloc(3 * 8192 * 2);
  // zero-init block (single memset)
  char* zbase    = ws + o;
  float* molr    = (float*)alloc((u64)NMOL * DF * 4);
  int* mcnt      = (int*)alloc(NMOL * 4);
  u64 zbytes     = (u64)((ws + o) - zbase);
  int* counts    = (int*)alloc((u64)NA * 4);
  int* row_ptr   = (int*)alloc((u64)(NA + 1) * 4);
  int* mrow      = (int*)alloc((NMOL + 1) * 4);
  unsigned* ds_pack = (unsigned*)alloc((u64)NE * 4);
  int* mol_sorted = (int*)alloc((u64)NA * 4);
  int* scan_tmp  = (int*)alloc((u64)NA * 4);
  int* blk_sums  = (int*)alloc(64 * 4);
  int* ntmp      = (int*)alloc((u64)NA * 4);
  int* nblk      = (int*)alloc(64 * 4);
  int* orow      = (int*)alloc((u64)(NA + 1) * 4);
  int* orow2     = (int*)alloc((u64)NA * 4);
  ushort_t* H    = (ushort_t*)alloc((u64)NRNG * NCH * RNG * 2);
  ushort_t* Orel = (ushort_t*)alloc((u64)NCH * NA * 2);
  unsigned* MH   = (unsigned*)alloc((u64)NCHM * 256 * 4);
  (void)ws_size; (void)in_sizes; (void)n_in; (void)out_size;

  const int NSCAN = (NA + 1023) / 1024;   // 49

  hipMemsetAsync(zbase, 0, zbytes, stream);

  hist_all<<<HISTB, 256, 0, stream>>>(dst, mol_ids, Win, Wh, Wout,
                                      WpB, WhB, WoB, H, MH, mcnt);
  col_scan<<<(NA + 255) / 256, 256, 0, stream>>>(H, Orel, counts);
  scan_phase1<<<NSCAN, 1024, 0, stream>>>(counts, scan_tmp, blk_sums, mcnt, mrow);
  scan_phase3<<<NSCAN, 1024, 0, stream>>>(scan_tmp, blk_sums, row_ptr, ntmp, nblk);
  nscan_p3<<<NSCAN, 1024, 0, stream>>>(ntmp, nblk, row_ptr, orow, orow2);
  scat_all<<<SCATB, 256, 0, stream>>>(dst, src, row_ptr, Orel, ds_pack,
                                      mol_ids, mrow, MH, mol_sorted);

  node_proj<<<NPB, 256, 0, stream>>>(states, WpB, b_in, PQb);
  for (int t = 0; t < NSTEP; t++) {
    edge_msg<<<EBLK, 256, 0, stream>>>(
        PQb, WhB + t * 4096, WoB + t * 8192,
        b_h + t * 64, b_out + t * 128, ds_pack, orow2, m_buf);
    if (t < NSTEP - 1) {
      agg_proj<<<(NA + 63) / 64, 256, 0, stream>>>(m_buf, orow,
                                                   WpB + (t + 1) * 16384,
                                                   b_in + (t + 1) * 64, PQb);
    } else {
      agg_mol2<<<(NA + 63) / 64, 256, 0, stream>>>(m_buf, orow, mol_sorted,
                                                   mol_ids, molr);
    }
  }
  final_mlp<<<NMOL, 64, 0, stream>>>(molr, fc1_w, fc1_b, fc2_w, fc2_b, out_w, out_b,
                                     (float*)d_out);
}

// Round 8
// 290.724 us; speedup vs baseline: 1.2913x; 1.2913x over previous
//
#include <hip/hip_runtime.h>

typedef unsigned long long u64;
typedef unsigned short ushort_t;

#define NA 50000
#define NE 400000
#define DF 128
#define HID 64
#define NMOL 256
#define NOUT 32
#define NSTEP 3
#define NPB 782  // node_proj blocks: ceil(NA/64)

// ---- atomic-free sort geometry ----
#define RNG 8192          // dst bins per range slice
#define NRNG 7            // ceil(NA/RNG)
#define NCH 32            // edge chunks (32: halves H/Orel traffic vs 64)
#define CHUNK 12500       // NE/NCH (< 65536 so u16 histograms stay valid)
#define NCHM 16           // mol chunks
#define CHM 3125          // NA/NCHM
#define NWB 336           // weight-pack blocks: 86016/256
#define HISTB (NRNG*NCH + NCHM + NWB)   // 576
#define SCATB (NRNG*NCH + NCHM)         // 240
#define MBUF_ROWS 160000  // 4-edge windows: R <= NE/4 + NA = 150000 (+margin)

// ---- persistent edge_msg geometry ----
#define NT (NE / 16)      // 25000 tiles of 16 edges
#define EBLK 1024         // persistent blocks
#define EGW (EBLK * 4)    // 4096 grid waves

typedef __attribute__((ext_vector_type(8))) unsigned short ushort8;
typedef __attribute__((ext_vector_type(4))) float f32x4;
typedef __attribute__((ext_vector_type(8))) _Float16 half8;
typedef __attribute__((ext_vector_type(2))) _Float16 half2_t;
typedef __attribute__((ext_vector_type(2))) __fp16 fp16x2;

static __device__ __forceinline__ ushort_t f2h(float f) {
  union { _Float16 h; ushort_t u; } v; v.h = (_Float16)f; return v.u;
}
static __device__ __forceinline__ float hlo(unsigned d) {
  union { unsigned u; half2_t h; } v; v.u = d; return (float)v.h[0];
}
static __device__ __forceinline__ float hhi(unsigned d) {
  union { unsigned u; half2_t h; } v; v.u = d; return (float)v.h[1];
}
static __device__ __forceinline__ unsigned pkrtz(float a, float b) {
  union { fp16x2 h; unsigned u; } v;
  v.h = __builtin_amdgcn_cvt_pkrtz(a, b);
  return v.u;
}

// ---- hist_all: dst-range histograms + mol histograms + weight pack --------
__global__ __launch_bounds__(256) void hist_all(
    const int* __restrict__ dst, const int* __restrict__ mol_ids,
    const float* __restrict__ Win, const float* __restrict__ Wh,
    const float* __restrict__ Wout,
    ushort_t* __restrict__ WpB, ushort_t* __restrict__ WhB,
    ushort_t* __restrict__ WoB,
    ushort_t* __restrict__ H, unsigned* __restrict__ MH,
    int* __restrict__ mcnt) {
  __shared__ unsigned hist[RNG];
  const int b = blockIdx.x, t = threadIdx.x;
  if (b < NRNG * NCH) {
    const int r = b / NCH, c = b % NCH;
    const int lo = r * RNG;
    for (int i = t; i < RNG; i += 256) hist[i] = 0;
    __syncthreads();
    const int base = c * CHUNK;
    for (int k = t; k < CHUNK; k += 256) {
      int d = dst[base + k];
      unsigned rel = (unsigned)(d - lo);
      if (rel < RNG) atomicAdd(&hist[rel], 1u);
    }
    __syncthreads();
    ushort_t* Hp = H + (u64)b * RNG;
    for (int i = t; i < RNG; i += 256) Hp[i] = (ushort_t)hist[i];
    return;
  }
  int b2 = b - NRNG * NCH;
  if (b2 < NCHM) {
    if (t < 256) hist[t] = 0;
    __syncthreads();
    const int base = b2 * CHM;
    for (int k = t; k < CHM; k += 256) atomicAdd(&hist[mol_ids[base + k]], 1u);
    __syncthreads();
    if (t < 256) {
      MH[b2 * 256 + t] = hist[t];
      if (hist[t]) atomicAdd(&mcnt[t], (int)hist[t]);
    }
    return;
  }
  // ---- weight pack (fp16 B-frag order) ----
  int g = (b2 - NCHM) * 256 + t;
  if (g < 3 * 16384) {
    int tt = g / 16384, r = g % 16384;
    int j = r & 7, lane = (r >> 3) & 63, f = r >> 9;
    int kc = f & 3, nt = f >> 2;
    int k = kc * 32 + (lane >> 4) * 8 + j;
    int n = nt * 16 + (lane & 15);
    float v = (n < 64) ? Win[tt * 16384 + k * 64 + n]
                       : Win[tt * 16384 + (128 + k) * 64 + (n - 64)];
    WpB[g] = f2h(v);
  }
  int g2 = g - 3 * 16384;
  if (g2 >= 0 && g2 < 3 * 4096) {
    int tt = g2 / 4096, r = g2 % 4096;
    int j = r & 7, lane = (r >> 3) & 63, f = r >> 9;
    int kc = f & 1, nt = f >> 1;
    int k = kc * 32 + (lane >> 4) * 8 + j;
    int n = nt * 16 + (lane & 15);
    WhB[g2] = f2h(Wh[tt * 4096 + k * 64 + n]);
  }
  int g3 = g2 - 3 * 4096;
  if (g3 >= 0 && g3 < 3 * 8192) {
    int tt = g3 / 8192, r = g3 % 8192;
    int j = r & 7, lane = (r >> 3) & 63, f = r >> 9;
    int kc = f & 1, nt = f >> 1;
    int k = kc * 32 + (lane >> 4) * 8 + j;
    int n = nt * 16 + (lane & 15);
    WoB[g3] = f2h(Wout[tt * 8192 + k * 128 + n]);
  }
}

// ---- col_scan: per-bin prefix over chunks -> Orel[c][bin], counts[bin] ----
__global__ void col_scan(const ushort_t* __restrict__ H,
                         ushort_t* __restrict__ Orel, int* __restrict__ counts) {
  int bidx = blockIdx.x * 256 + threadIdx.x;
  if (bidx >= NA) return;
  int r = bidx >> 13, i = bidx & (RNG - 1);
  const ushort_t* Hp = H + ((u64)r * NCH) * RNG + i;
  unsigned acc = 0;
  for (int c = 0; c < NCH; c++) {
    Orel[(u64)c * NA + bidx] = (ushort_t)acc;
    acc += Hp[(u64)c * RNG];
  }
  counts[bidx] = (int)acc;
}

// per-1024-block inclusive scan of counts; last block also scans mol histogram
__global__ void scan_phase1(const int* __restrict__ counts, int* __restrict__ tmp,
                            int* __restrict__ blk,
                            const int* __restrict__ mcnt, int* __restrict__ mrow) {
  __shared__ int sh[1024];
  int t = threadIdx.x;
  int i = blockIdx.x * 1024 + t;
  sh[t] = (i < NA) ? counts[i] : 0;
  __syncthreads();
  for (int off = 1; off < 1024; off <<= 1) {
    int x = (t >= off) ? sh[t - off] : 0;
    __syncthreads();
    sh[t] += x;
    __syncthreads();
  }
  if (i < NA) tmp[i] = sh[t];
  if (t == 1023) blk[blockIdx.x] = sh[1023];
  if (blockIdx.x == gridDim.x - 1) {  // fold in the molecule scan
    __syncthreads();
    sh[t] = (t < NMOL) ? mcnt[t] : 0;
    __syncthreads();
    for (int off = 1; off < NMOL; off <<= 1) {
      int x = (t >= off && t < NMOL) ? sh[t - off] : 0;
      __syncthreads();
      if (t < NMOL) sh[t] += x;
      __syncthreads();
    }
    if (t < NMOL) mrow[t + 1] = sh[t];
    if (t == 0) mrow[0] = 0;
  }
}

// row_ptr[i+1] = tmp[i] + prefix(blk); ALSO block-scan of per-dst window counts
// 4-edge windows: nwin(d) = ((re-1)>>2) - (rs>>2) + 1
__global__ void scan_phase3(const int* __restrict__ tmp, const int* __restrict__ blk,
                            int* __restrict__ row_ptr,
                            int* __restrict__ ntmp, int* __restrict__ nblk) {
  __shared__ int sh[1024];
  __shared__ int spre_sh;
  int t = threadIdx.x;
  int bid = blockIdx.x;
  if (t < 64) {
    int v = (t < bid) ? blk[t] : 0;  // bid <= 48 < 64
    for (int off = 32; off; off >>= 1) v += __shfl_down(v, off);
    if (t == 0) spre_sh = v;
  }
  __syncthreads();
  int spre = spre_sh;
  int i = bid * 1024 + t;
  int nwin = 0;
  if (i < NA) {
    int re = tmp[i] + spre;                           // row_ptr[i+1]
    int rs = (t == 0) ? spre : (tmp[i - 1] + spre);   // row_ptr[i]
    row_ptr[i + 1] = re;
    if (re > rs) nwin = ((re - 1) >> 2) - (rs >> 2) + 1;
  }
  if (i == 0) row_ptr[0] = 0;
  sh[t] = nwin;
  __syncthreads();
  for (int off = 1; off < 1024; off <<= 1) {
    int x = (t >= off) ? sh[t - off] : 0;
    __syncthreads();
    sh[t] += x;
    __syncthreads();
  }
  if (i < NA) ntmp[i] = sh[t];
  if (t == 1023) nblk[bid] = sh[1023];
}

// orow[i] = sub-run prefix; orow2[d] = orow[d] - (row_ptr[d]>>2)
__global__ void nscan_p3(const int* __restrict__ ntmp, const int* __restrict__ nblk,
                         const int* __restrict__ row_ptr,
                         int* __restrict__ orow, int* __restrict__ orow2) {
  __shared__ int spre_sh;
  int t = threadIdx.x;
  int bid = blockIdx.x;
  if (t < 64) {
    int v = (t < bid) ? nblk[t] : 0;  // bid <= 48 < 64
    for (int off = 32; off; off >>= 1) v += __shfl_down(v, off);
    if (t == 0) spre_sh = v;
  }
  __syncthreads();
  int spre = spre_sh;
  int i = bid * 1024 + t;
  if (i < NA) {
    orow[i + 1] = ntmp[i] + spre;
    int oi = (t == 0) ? spre : (ntmp[i - 1] + spre);  // orow[i]
    orow2[i] = oi - (row_ptr[i] >> 2);
  }
  if (i == 0) orow[0] = 0;
}

// ---- scat_all: atomic-free scatter via LDS ranks + offset table -----------
__global__ __launch_bounds__(256) void scat_all(
    const int* __restrict__ dst, const int* __restrict__ src,
    const int* __restrict__ row_ptr, const ushort_t* __restrict__ Orel,
    unsigned* __restrict__ ds_pack,
    const int* __restrict__ mol_ids, const int* __restrict__ mrow,
    const unsigned* __restrict__ MH, int* __restrict__ mol_sorted) {
  __shared__ unsigned cnt[RNG];
  __shared__ unsigned mbase[256];
  const int b = blockIdx.x, t = threadIdx.x;
  if (b < NRNG * NCH) {
    const int r = b / NCH, c = b % NCH;
    const int lo = r * RNG;
    for (int i = t; i < RNG; i += 256) cnt[i] = 0;
    __syncthreads();
    const int base = c * CHUNK;
    const ushort_t* Op = Orel + (u64)c * NA;
    for (int k = t; k < CHUNK; k += 256) {
      int e = base + k;
      int d = dst[e];
      unsigned rel = (unsigned)(d - lo);
      if (rel < RNG) {
        unsigned lr = atomicAdd(&cnt[rel], 1u);
        int pos = row_ptr[d] + (int)Op[d] + (int)lr;
        ds_pack[pos] = ((unsigned)d << 16) | (unsigned)src[e];
      }
    }
    return;
  }
  const int c2 = b - NRNG * NCH;  // mol chunk
  if (t < 256) {
    unsigned s = (unsigned)mrow[t];
    for (int cp = 0; cp < c2; cp++) s += MH[cp * 256 + t];
    mbase[t] = s;
    cnt[t] = 0;
  }
  __syncthreads();
  const int base = c2 * CHM;
  for (int k = t; k < CHM; k += 256) {
    int a = base + k;
    int m = mol_ids[a];
    unsigned lr = atomicAdd(&cnt[m], 1u);
    mol_sorted[mbase[m] + lr] = a;
  }
}

// -------- node projection (step 0): states f32 -> PQb fp16 -----------------
__global__ __launch_bounds__(256) void node_proj(
    const float* __restrict__ s_in, const ushort_t* __restrict__ WpB,
    const float* __restrict__ b_in, ushort_t* __restrict__ PQb) {
  const int t = threadIdx.x;
  const int lane = t & 63, wv = t >> 6, quad = lane >> 4, l15 = lane & 15;
  const int n0 = blockIdx.x * 64 + wv * 16;
  int n = n0 + l15; if (n >= NA) n = NA - 1;
  union { half8 v; unsigned d[4]; } a[4];
#pragma unroll
  for (int c = 0; c < 4; c++) {
    const float* p = s_in + (u64)n * 128 + c * 32 + quad * 8;
    float4 f0 = *(const float4*)(p);
    float4 f1 = *(const float4*)(p + 4);
    a[c].d[0] = pkrtz(f0.x, f0.y);
    a[c].d[1] = pkrtz(f0.z, f0.w);
    a[c].d[2] = pkrtz(f1.x, f1.y);
    a[c].d[3] = pkrtz(f1.z, f1.w);
  }
  float binv[4];
#pragma unroll
  for (int nt = 0; nt < 4; nt++) binv[nt] = b_in[nt * 16 + l15];
#pragma unroll
  for (int nt = 0; nt < 8; nt++) {
    f32x4 acc = {0.f, 0.f, 0.f, 0.f};
#pragma unroll
    for (int c = 0; c < 4; c++) {
      half8 b = *(const half8*)&WpB[((nt * 4 + c) * 64 + lane) * 8];
      acc = __builtin_amdgcn_mfma_f32_16x16x32_f16(a[c].v, b, acc, 0, 0, 0);
    }
    float bias = (nt < 4) ? binv[nt] : 0.f;
#pragma unroll
    for (int r = 0; r < 4; r++) {
      int nn = n0 + quad * 4 + r;
      if (nn < NA) PQb[(u64)nn * 128 + nt * 16 + l15] = f2h(acc[r] + bias);
    }
  }
}

// ------ persistent fused edge MLP (fp16 MFMA) -> packed-fp16 sub-run sums --
// 4096 grid waves, each grid-strides over 16-edge tiles with a 3-stage
// software pipeline: pk[t+2] loading | gathers[t+1] loading | compute[t].
__global__ __launch_bounds__(256) void edge_msg(
    const ushort_t* __restrict__ PQb,
    const ushort_t* __restrict__ WhB, const ushort_t* __restrict__ WoB,
    const float* __restrict__ b_h, const float* __restrict__ b_out,
    const unsigned* __restrict__ ds_pack, const int* __restrict__ orow2,
    unsigned* __restrict__ m_buf) {
  __shared__ ushort_t h2s[4][16 * 72];  // per-wave 16 x 64 fp16 repack tile
  const int t = threadIdx.x;
  const int lane = t & 63, wv = t >> 6, quad = lane >> 4, l15 = lane & 15;
  const int gw = blockIdx.x * 4 + wv;   // global wave id in [0, EGW)

  float bh[4], bo[8];
#pragma unroll
  for (int nt = 0; nt < 4; nt++) bh[nt] = b_h[nt * 16 + l15];
#pragma unroll
  for (int nt = 0; nt < 8; nt++) bo[nt] = b_out[nt * 16 + l15];

  ushort_t* hb = h2s[wv];
  const int colq = quad * 8;
  const half2_t z2 = {(_Float16)0.f, (_Float16)0.f};

  struct Ctx {
    int e;            // this lane's edge index (tile*16 + l15)
    unsigned pk;      // (dst<<16)|src
    int o;            // sub-run row of edge e
    ushort8 pv0, pv1, qv0, qv1;
  };

  auto load_pk = [&](Ctx& c, int tile) {
    c.e = tile * 16 + l15;
    c.pk = ds_pack[c.e];
  };
  auto gather = [&](Ctx& c) {
    u64 da = c.pk >> 16, sa = c.pk & 0xffffu;
    c.o = orow2[da] + (c.e >> 2);
    c.pv0 = *(const ushort8*)&PQb[da * 128 + colq];
    c.pv1 = *(const ushort8*)&PQb[da * 128 + 32 + colq];
    c.qv0 = *(const ushort8*)&PQb[sa * 128 + 64 + colq];
    c.qv1 = *(const ushort8*)&PQb[sa * 128 + 96 + colq];
  };
  auto compute = [&](Ctx& c) {
    union UPQ { ushort8 u; half2_t h[4]; };
    UPQ P0, P1, Q0, Q1;
    P0.u = c.pv0; P1.u = c.pv1; Q0.u = c.qv0; Q1.u = c.qv1;
    union { half8 v; half2_t h[4]; } a1[2];
#pragma unroll
    for (int k = 0; k < 4; k++) {
      half2_t s0 = P0.h[k] + Q0.h[k];
      half2_t s1 = P1.h[k] + Q1.h[k];
      a1[0].h[k] = __builtin_elementwise_max(s0, z2);
      a1[1].h[k] = __builtin_elementwise_max(s1, z2);
    }
    // h2 = relu(h1 @ Wh + b_h) -> wave-private LDS repack
#pragma unroll
    for (int nt = 0; nt < 4; nt++) {
      f32x4 acc = {0.f, 0.f, 0.f, 0.f};
#pragma unroll
      for (int cc = 0; cc < 2; cc++) {
        half8 b = *(const half8*)&WhB[((nt * 2 + cc) * 64 + lane) * 8];
        acc = __builtin_amdgcn_mfma_f32_16x16x32_f16(a1[cc].v, b, acc, 0, 0, 0);
      }
#pragma unroll
      for (int r = 0; r < 4; r++)
        hb[(quad * 4 + r) * 72 + nt * 16 + l15] =
            f2h(fmaxf(acc[r] + bh[nt], 0.f));
    }
    half8 a2[2];
    a2[0] = *(const half8*)&hb[l15 * 72 + colq];
    a2[1] = *(const half8*)&hb[l15 * 72 + 32 + colq];
    // m = relu(h2 @ Wout + b_out)
    f32x4 acc2[8];
#pragma unroll
    for (int nt = 0; nt < 8; nt++) {
      f32x4 acc = {0.f, 0.f, 0.f, 0.f};
#pragma unroll
      for (int cc = 0; cc < 2; cc++) {
        half8 b = *(const half8*)&WoB[((nt * 2 + cc) * 64 + lane) * 8];
        acc = __builtin_amdgcn_mfma_f32_16x16x32_f16(a2[cc], b, acc, 0, 0, 0);
      }
      acc2[nt] = acc;
    }
    // segmented sub-run flush over the quad's 4 edges (pks/rows via shfl)
    int pkr[4], orr[4];
#pragma unroll
    for (int r = 0; r < 4; r++) {
      int srcl = (lane & 48) + quad * 4 + r;
      pkr[r] = __shfl((int)c.pk, srcl);
      orr[r] = __shfl(c.o, srcl);
    }
    unsigned prev = ((unsigned)pkr[0]) >> 16;
    int orow_ = orr[0];
    float run[8];
#pragma unroll
    for (int nt = 0; nt < 8; nt++) run[nt] = 0.f;
#pragma unroll
    for (int r = 0; r < 4; r++) {
      unsigned dcur = ((unsigned)pkr[r]) >> 16;
      if (dcur != prev) {
        unsigned* rowp = m_buf + (u64)orow_ * 64;
#pragma unroll
        for (int k = 0; k < 4; k++)
          rowp[k * 16 + l15] = pkrtz(run[2 * k], run[2 * k + 1]);
#pragma unroll
        for (int nt = 0; nt < 8; nt++) run[nt] = 0.f;
        prev = dcur; orow_ = orr[r];
      }
#pragma unroll
      for (int nt = 0; nt < 8; nt++)
        run[nt] += fmaxf(acc2[nt][r] + bo[nt], 0.f);
    }
    unsigned* rowp = m_buf + (u64)orow_ * 64;
#pragma unroll
    for (int k = 0; k < 4; k++)
      rowp[k * 16 + l15] = pkrtz(run[2 * k], run[2 * k + 1]);
  };

  // ---- 3-stage pipelined grid-stride loop ----
  Ctx A, B, C;
  int tc = gw;                 // gw < EGW <= NT always
  load_pk(A, tc);
  int tb = tc + EGW;
  if (tb < NT) load_pk(B, tb);
  gather(A);
  while (tc < NT) {
    int tn = tc + EGW;
    if (tn < NT) gather(B);
    int t2 = tn + EGW;
    if (t2 < NT) load_pk(C, t2);
    compute(A);
    A = B; B = C;
    tc = tn;
  }
}

// ---- fused dst aggregation + projection; bounds staged in LDS -------------
__global__ __launch_bounds__(256) void agg_proj(
    const unsigned* __restrict__ m_buf, const int* __restrict__ orow,
    const ushort_t* __restrict__ WpB, const float* __restrict__ b_in,
    ushort_t* __restrict__ PQb) {
  __shared__ ushort_t a_s[64 * 136];  // 64 rows x 128 fp16, pitch 136
  __shared__ int obs_s[65];
  const int t = threadIdx.x;
  const int lane = t & 63, wv = t >> 6, quad = lane >> 4, l15 = lane & 15;
  const int n0 = blockIdx.x * 64;
  if (t < 65) {
    int idx = n0 + t; if (idx > NA) idx = NA;
    obs_s[t] = orow[idx];
  }
  __syncthreads();

  for (int r = 0; r < 16; r++) {
    const int d = n0 + wv * 16 + r;
    float s0 = 0.f, s1 = 0.f;
    if (d < NA) {
      int ob = obs_s[wv * 16 + r], oe = obs_s[wv * 16 + r + 1];
      int n = oe - ob;
      float t0 = 0.f, t1 = 0.f, u0 = 0.f, u1 = 0.f, v0 = 0.f, v1 = 0.f;
      int full = n & ~3;
      int e = ob;
      for (; e < ob + full; e += 4) {
        unsigned w0 = m_buf[(u64)(e + 0) * 64 + lane];
        unsigned w1 = m_buf[(u64)(e + 1) * 64 + lane];
        unsigned w2 = m_buf[(u64)(e + 2) * 64 + lane];
        unsigned w3 = m_buf[(u64)(e + 3) * 64 + lane];
        s0 += hlo(w0); s1 += hhi(w0);
        t0 += hlo(w1); t1 += hhi(w1);
        u0 += hlo(w2); u1 += hhi(w2);
        v0 += hlo(w3); v1 += hhi(w3);
      }
      int rem = n - full;
      if (rem > 0) {
        int i1 = (rem > 1) ? e + 1 : e;
        int i2 = (rem > 2) ? e + 2 : e;
        unsigned w0 = m_buf[(u64)e * 64 + lane];
        unsigned w1 = m_buf[(u64)i1 * 64 + lane];
        unsigned w2 = m_buf[(u64)i2 * 64 + lane];
        s0 += hlo(w0); s1 += hhi(w0);
        if (rem > 1) { t0 += hlo(w1); t1 += hhi(w1); }
        if (rem > 2) { u0 += hlo(w2); u1 += hhi(w2); }
      }
      s0 = (s0 + t0) + (u0 + v0);
      s1 = (s1 + t1) + (u1 + v1);
    }
    const int row = wv * 16 + r;
    a_s[row * 136 + quad * 32 + l15] = f2h(s0);
    a_s[row * 136 + quad * 32 + 16 + l15] = f2h(s1);
  }
  // wave-private tile: same-wave LDS RAW ordered by lgkmcnt, no barrier

  float binv[4];
#pragma unroll
  for (int nt = 0; nt < 4; nt++) binv[nt] = b_in[nt * 16 + l15];
  half8 a[4];
#pragma unroll
  for (int c = 0; c < 4; c++)
    a[c] = *(const half8*)&a_s[(wv * 16 + l15) * 136 + c * 32 + quad * 8];
#pragma unroll
  for (int nt = 0; nt < 8; nt++) {
    f32x4 acc = {0.f, 0.f, 0.f, 0.f};
#pragma unroll
    for (int c = 0; c < 4; c++) {
      half8 b = *(const half8*)&WpB[((nt * 4 + c) * 64 + lane) * 8];
      acc = __builtin_amdgcn_mfma_f32_16x16x32_f16(a[c], b, acc, 0, 0, 0);
    }
    float bias = (nt < 4) ? binv[nt] : 0.f;
#pragma unroll
    for (int r = 0; r < 4; r++) {
      int nn = n0 + wv * 16 + quad * 4 + r;
      if (nn < NA) PQb[(u64)nn * 128 + nt * 16 + l15] = f2h(acc[r] + bias);
    }
  }
}

// ---- final aggregation: m_buf sub-runs -> per-mol sums; bounds in LDS -----
__global__ __launch_bounds__(256) void agg_mol2(
    const unsigned* __restrict__ m_buf, const int* __restrict__ orow,
    const int* __restrict__ mol_sorted, const int* __restrict__ mol_ids,
    float* __restrict__ mol_repr) {
  __shared__ int mids[64], obs[64], oes[64];
  const int t = threadIdx.x;
  const int lane = t & 63, wv = t >> 6;
  const int base = blockIdx.x * 64;
  if (t < 64) {
    int idx = base + t;
    int r = (idx < NA) ? mol_sorted[idx] : 0;
    mids[t] = (idx < NA) ? mol_ids[r] : -1;
    obs[t] = orow[r];
    oes[t] = orow[r + 1];
  }
  __syncthreads();
  const int c0 = (lane >> 4) * 32 + (lane & 15);  // unpacked cols c0, c0+16
  float r0 = 0.f, r1 = 0.f;
  int prev = mids[wv * 16];
  for (int i = 0; i < 16; i++) {
    int li = wv * 16 + i;
    int m = mids[li];
    if (m != prev) {
      if (prev >= 0) {
        atomicAdd(&mol_repr[(u64)prev * 128 + c0], r0);
        atomicAdd(&mol_repr[(u64)prev * 128 + c0 + 16], r1);
      }
      r0 = 0.f; r1 = 0.f; prev = m;
    }
    if (m >= 0) {
      int ob = obs[li], oe = oes[li];
      int n = oe - ob;
      float t0 = 0.f, t1 = 0.f, u0 = 0.f, u1 = 0.f, v0 = 0.f, v1 = 0.f;
      int full = n & ~3;
      int e = ob;
      for (; e < ob + full; e += 4) {
        unsigned w0 = m_buf[(u64)(e + 0) * 64 + lane];
        unsigned w1 = m_buf[(u64)(e + 1) * 64 + lane];
        unsigned w2 = m_buf[(u64)(e + 2) * 64 + lane];
        unsigned w3 = m_buf[(u64)(e + 3) * 64 + lane];
        r0 += hlo(w0); r1 += hhi(w0);
        t0 += hlo(w1); t1 += hhi(w1);
        u0 += hlo(w2); u1 += hhi(w2);
        v0 += hlo(w3); v1 += hhi(w3);
      }
      int rem = n - full;
      if (rem > 0) {
        int i1 = (rem > 1) ? e + 1 : e;
        int i2 = (rem > 2) ? e + 2 : e;
        unsigned w0 = m_buf[(u64)e * 64 + lane];
        unsigned w1 = m_buf[(u64)i1 * 64 + lane];
        unsigned w2 = m_buf[(u64)i2 * 64 + lane];
        r0 += hlo(w0); r1 += hhi(w0);
        if (rem > 1) { t0 += hlo(w1); t1 += hhi(w1); }
        if (rem > 2) { u0 += hlo(w2); u1 += hhi(w2); }
      }
      r0 += (t0 + u0) + v0;
      r1 += (t1 + u1) + v1;
    }
  }
  if (prev >= 0) {
    atomicAdd(&mol_repr[(u64)prev * 128 + c0], r0);
    atomicAdd(&mol_repr[(u64)prev * 128 + c0 + 16], r1);
  }
}

// ---------------- final tiny MLP per molecule ----------------
__global__ void final_mlp(const float* __restrict__ mol_repr,
                          const float* __restrict__ fc1_w, const float* __restrict__ fc1_b,
                          const float* __restrict__ fc2_w, const float* __restrict__ fc2_b,
                          const float* __restrict__ out_w, const float* __restrict__ out_b,
                          float* __restrict__ out) {
  int m = blockIdx.x, j = threadIdx.x;
  __shared__ float h1sh[64], h2sh[64];
  const float* mr = mol_repr + (u64)m * DF;
  float acc = fc1_b[j];
  for (int d = 0; d < DF; d++) acc = fmaf(mr[d], fc1_w[d * 64 + j], acc);
  h1sh[j] = fmaxf(acc, 0.f);
  __syncthreads();
  acc = fc2_b[j];
  for (int k = 0; k < 64; k++) acc = fmaf(h1sh[k], fc2_w[k * 64 + j], acc);
  h2sh[j] = fmaxf(acc, 0.f);
  __syncthreads();
  if (j < NOUT) {
    acc = out_b[j];
    for (int k = 0; k < 64; k++) acc = fmaf(h2sh[k], out_w[k * NOUT + j], acc);
    out[(u64)m * NOUT + j] = acc;
  }
}

extern "C" void kernel_launch(void* const* d_in, const int* in_sizes, int n_in,
                              void* d_out, int out_size, void* d_ws, size_t ws_size,
                              hipStream_t stream) {
  const float* states = (const float*)d_in[0];
  const float* Win    = (const float*)d_in[1];
  const float* b_in   = (const float*)d_in[2];
  const float* Wh     = (const float*)d_in[3];
  const float* b_h    = (const float*)d_in[4];
  const float* Wout   = (const float*)d_in[5];
  const float* b_out  = (const float*)d_in[6];
  const float* fc1_w  = (const float*)d_in[7];
  const float* fc1_b  = (const float*)d_in[8];
  const float* fc2_w  = (const float*)d_in[9];
  const float* fc2_b  = (const float*)d_in[10];
  const float* out_w  = (const float*)d_in[11];
  const float* out_b  = (const float*)d_in[12];
  const int* src      = (const int*)d_in[13];
  const int* dst      = (const int*)d_in[14];
  const int* mol_ids  = (const int*)d_in[15];

  char* ws = (char*)d_ws;
  u64 o = 0;
  auto alloc = [&](u64 bytes) {
    void* p = ws + o;
    o += (bytes + 255) & ~255ull;
    return p;
  };
  unsigned* m_buf = (unsigned*)alloc((u64)MBUF_ROWS * 64 * 4);
  ushort_t* PQb  = (ushort_t*)alloc((u64)NA * DF * 2);
  ushort_t* WpB  = (ushort_t*)alloc(3 * 16384 * 2);
  ushort_t* WhB  = (ushort_t*)alloc(3 * 4096 * 2);
  ushort_t* WoB  = (ushort_t*)alloc(3 * 8192 * 2);
  // zero-init block (single memset)
  char* zbase    = ws + o;
  float* molr    = (float*)alloc((u64)NMOL * DF * 4);
  int* mcnt      = (int*)alloc(NMOL * 4);
  u64 zbytes     = (u64)((ws + o) - zbase);
  int* counts    = (int*)alloc((u64)NA * 4);
  int* row_ptr   = (int*)alloc((u64)(NA + 1) * 4);
  int* mrow      = (int*)alloc((NMOL + 1) * 4);
  unsigned* ds_pack = (unsigned*)alloc((u64)NE * 4);
  int* mol_sorted = (int*)alloc((u64)NA * 4);
  int* scan_tmp  = (int*)alloc((u64)NA * 4);
  int* blk_sums  = (int*)alloc(64 * 4);
  int* ntmp      = (int*)alloc((u64)NA * 4);
  int* nblk      = (int*)alloc(64 * 4);
  int* orow      = (int*)alloc((u64)(NA + 1) * 4);
  int* orow2     = (int*)alloc((u64)NA * 4);
  ushort_t* H    = (ushort_t*)alloc((u64)NRNG * NCH * RNG * 2);
  ushort_t* Orel = (ushort_t*)alloc((u64)NCH * NA * 2);
  unsigned* MH   = (unsigned*)alloc((u64)NCHM * 256 * 4);
  (void)ws_size; (void)in_sizes; (void)n_in; (void)out_size;

  const int NSCAN = (NA + 1023) / 1024;   // 49

  hipMemsetAsync(zbase, 0, zbytes, stream);

  hist_all<<<HISTB, 256, 0, stream>>>(dst, mol_ids, Win, Wh, Wout,
                                      WpB, WhB, WoB, H, MH, mcnt);
  col_scan<<<(NA + 255) / 256, 256, 0, stream>>>(H, Orel, counts);
  scan_phase1<<<NSCAN, 1024, 0, stream>>>(counts, scan_tmp, blk_sums, mcnt, mrow);
  scan_phase3<<<NSCAN, 1024, 0, stream>>>(scan_tmp, blk_sums, row_ptr, ntmp, nblk);
  nscan_p3<<<NSCAN, 1024, 0, stream>>>(ntmp, nblk, row_ptr, orow, orow2);
  scat_all<<<SCATB, 256, 0, stream>>>(dst, src, row_ptr, Orel, ds_pack,
                                      mol_ids, mrow, MH, mol_sorted);

  node_proj<<<NPB, 256, 0, stream>>>(states, WpB, b_in, PQb);
  for (int t = 0; t < NSTEP; t++) {
    edge_msg<<<EBLK, 256, 0, stream>>>(
        PQb, WhB + t * 4096, WoB + t * 8192,
        b_h + t * 64, b_out + t * 128, ds_pack, orow2, m_buf);
    if (t < NSTEP - 1) {
      agg_proj<<<(NA + 63) / 64, 256, 0, stream>>>(m_buf, orow,
                                                   WpB + (t + 1) * 16384,
                                                   b_in + (t + 1) * 64, PQb);
    } else {
      agg_mol2<<<(NA + 63) / 64, 256, 0, stream>>>(m_buf, orow, mol_sorted,
                                                   mol_ids, molr);
    }
  }
  final_mlp<<<NMOL, 64, 0, stream>>>(molr, fc1_w, fc1_b, fc2_w, fc2_b, out_w, out_b,
                                     (float*)d_out);
}

// Round 9
// 289.552 us; speedup vs baseline: 1.2965x; 1.0040x over previous
//
#include <hip/hip_runtime.h>

typedef unsigned long long u64;
typedef unsigned short ushort_t;

#define NA 50000
#define NE 400000
#define DF 128
#define HID 64
#define NMOL 256
#define NOUT 32
#define NSTEP 3
#define NPB 782  // node_proj blocks: ceil(NA/64)

// ---- atomic-free sort geometry ----
#define RNG 8192          // dst bins per range slice
#define NRNG 7            // ceil(NA/RNG)
#define NCH 64            // edge chunks (64: keeps scat/hist > 1 block/CU)
#define CHUNK 6250        // NE/NCH
#define NCHM 16           // mol chunks
#define CHM 3125          // NA/NCHM
#define NWB 336           // weight-pack blocks: 86016/256
#define HISTB (NRNG*NCH + NCHM + NWB)   // 800
#define SCATB (NRNG*NCH + NCHM)         // 464
#define MBUF_ROWS 160000  // 4-edge windows: R <= NE/4 + NA = 150000 (+margin)

// ---- persistent edge_msg geometry ----
#define NT (NE / 16)      // 25000 tiles of 16 edges
#define EBLK 1536         // persistent blocks: 6 blocks/CU = 24 waves/CU
#define EGW (EBLK * 4)    // 6144 grid waves

typedef __attribute__((ext_vector_type(8))) unsigned short ushort8;
typedef __attribute__((ext_vector_type(4))) float f32x4;
typedef __attribute__((ext_vector_type(8))) _Float16 half8;
typedef __attribute__((ext_vector_type(2))) _Float16 half2_t;
typedef __attribute__((ext_vector_type(2))) __fp16 fp16x2;

static __device__ __forceinline__ ushort_t f2h(float f) {
  union { _Float16 h; ushort_t u; } v; v.h = (_Float16)f; return v.u;
}
static __device__ __forceinline__ float hlo(unsigned d) {
  union { unsigned u; half2_t h; } v; v.u = d; return (float)v.h[0];
}
static __device__ __forceinline__ float hhi(unsigned d) {
  union { unsigned u; half2_t h; } v; v.u = d; return (float)v.h[1];
}
static __device__ __forceinline__ unsigned pkrtz(float a, float b) {
  union { fp16x2 h; unsigned u; } v;
  v.h = __builtin_amdgcn_cvt_pkrtz(a, b);
  return v.u;
}

// ---- hist_all: dst-range histograms + mol histograms + weight pack --------
__global__ __launch_bounds__(256) void hist_all(
    const int* __restrict__ dst, const int* __restrict__ mol_ids,
    const float* __restrict__ Win, const float* __restrict__ Wh,
    const float* __restrict__ Wout,
    ushort_t* __restrict__ WpB, ushort_t* __restrict__ WhB,
    ushort_t* __restrict__ WoB,
    ushort_t* __restrict__ H, unsigned* __restrict__ MH,
    int* __restrict__ mcnt) {
  __shared__ unsigned hist[RNG];
  const int b = blockIdx.x, t = threadIdx.x;
  if (b < NRNG * NCH) {
    const int r = b / NCH, c = b % NCH;
    const int lo = r * RNG;
    for (int i = t; i < RNG; i += 256) hist[i] = 0;
    __syncthreads();
    const int base = c * CHUNK;
    for (int k = t; k < CHUNK; k += 256) {
      int d = dst[base + k];
      unsigned rel = (unsigned)(d - lo);
      if (rel < RNG) atomicAdd(&hist[rel], 1u);
    }
    __syncthreads();
    ushort_t* Hp = H + (u64)b * RNG;
    for (int i = t; i < RNG; i += 256) Hp[i] = (ushort_t)hist[i];
    return;
  }
  int b2 = b - NRNG * NCH;
  if (b2 < NCHM) {
    if (t < 256) hist[t] = 0;
    __syncthreads();
    const int base = b2 * CHM;
    for (int k = t; k < CHM; k += 256) atomicAdd(&hist[mol_ids[base + k]], 1u);
    __syncthreads();
    if (t < 256) {
      MH[b2 * 256 + t] = hist[t];
      if (hist[t]) atomicAdd(&mcnt[t], (int)hist[t]);
    }
    return;
  }
  // ---- weight pack (fp16 B-frag order) ----
  int g = (b2 - NCHM) * 256 + t;
  if (g < 3 * 16384) {
    int tt = g / 16384, r = g % 16384;
    int j = r & 7, lane = (r >> 3) & 63, f = r >> 9;
    int kc = f & 3, nt = f >> 2;
    int k = kc * 32 + (lane >> 4) * 8 + j;
    int n = nt * 16 + (lane & 15);
    float v = (n < 64) ? Win[tt * 16384 + k * 64 + n]
                       : Win[tt * 16384 + (128 + k) * 64 + (n - 64)];
    WpB[g] = f2h(v);
  }
  int g2 = g - 3 * 16384;
  if (g2 >= 0 && g2 < 3 * 4096) {
    int tt = g2 / 4096, r = g2 % 4096;
    int j = r & 7, lane = (r >> 3) & 63, f = r >> 9;
    int kc = f & 1, nt = f >> 1;
    int k = kc * 32 + (lane >> 4) * 8 + j;
    int n = nt * 16 + (lane & 15);
    WhB[g2] = f2h(Wh[tt * 4096 + k * 64 + n]);
  }
  int g3 = g2 - 3 * 4096;
  if (g3 >= 0 && g3 < 3 * 8192) {
    int tt = g3 / 8192, r = g3 % 8192;
    int j = r & 7, lane = (r >> 3) & 63, f = r >> 9;
    int kc = f & 1, nt = f >> 1;
    int k = kc * 32 + (lane >> 4) * 8 + j;
    int n = nt * 16 + (lane & 15);
    WoB[g3] = f2h(Wout[tt * 8192 + k * 128 + n]);
  }
}

// ---- col_scan: per-bin prefix over chunks -> Orel[c][bin], counts[bin] ----
__global__ void col_scan(const ushort_t* __restrict__ H,
                         ushort_t* __restrict__ Orel, int* __restrict__ counts) {
  int bidx = blockIdx.x * 256 + threadIdx.x;
  if (bidx >= NA) return;
  int r = bidx >> 13, i = bidx & (RNG - 1);
  const ushort_t* Hp = H + ((u64)r * NCH) * RNG + i;
  unsigned acc = 0;
  for (int c = 0; c < NCH; c++) {
    Orel[(u64)c * NA + bidx] = (ushort_t)acc;
    acc += Hp[(u64)c * RNG];
  }
  counts[bidx] = (int)acc;
}

// per-1024-block inclusive scan of counts; last block also scans mol histogram
__global__ void scan_phase1(const int* __restrict__ counts, int* __restrict__ tmp,
                            int* __restrict__ blk,
                            const int* __restrict__ mcnt, int* __restrict__ mrow) {
  __shared__ int sh[1024];
  int t = threadIdx.x;
  int i = blockIdx.x * 1024 + t;
  sh[t] = (i < NA) ? counts[i] : 0;
  __syncthreads();
  for (int off = 1; off < 1024; off <<= 1) {
    int x = (t >= off) ? sh[t - off] : 0;
    __syncthreads();
    sh[t] += x;
    __syncthreads();
  }
  if (i < NA) tmp[i] = sh[t];
  if (t == 1023) blk[blockIdx.x] = sh[1023];
  if (blockIdx.x == gridDim.x - 1) {  // fold in the molecule scan
    __syncthreads();
    sh[t] = (t < NMOL) ? mcnt[t] : 0;
    __syncthreads();
    for (int off = 1; off < NMOL; off <<= 1) {
      int x = (t >= off && t < NMOL) ? sh[t - off] : 0;
      __syncthreads();
      if (t < NMOL) sh[t] += x;
      __syncthreads();
    }
    if (t < NMOL) mrow[t + 1] = sh[t];
    if (t == 0) mrow[0] = 0;
  }
}

// row_ptr[i+1] = tmp[i] + prefix(blk); ALSO block-scan of per-dst window counts
// 4-edge windows: nwin(d) = ((re-1)>>2) - (rs>>2) + 1
__global__ void scan_phase3(const int* __restrict__ tmp, const int* __restrict__ blk,
                            int* __restrict__ row_ptr,
                            int* __restrict__ ntmp, int* __restrict__ nblk) {
  __shared__ int sh[1024];
  __shared__ int spre_sh;
  int t = threadIdx.x;
  int bid = blockIdx.x;
  if (t < 64) {
    int v = (t < bid) ? blk[t] : 0;  // bid <= 48 < 64
    for (int off = 32; off; off >>= 1) v += __shfl_down(v, off);
    if (t == 0) spre_sh = v;
  }
  __syncthreads();
  int spre = spre_sh;
  int i = bid * 1024 + t;
  int nwin = 0;
  if (i < NA) {
    int re = tmp[i] + spre;                           // row_ptr[i+1]
    int rs = (t == 0) ? spre : (tmp[i - 1] + spre);   // row_ptr[i]
    row_ptr[i + 1] = re;
    if (re > rs) nwin = ((re - 1) >> 2) - (rs >> 2) + 1;
  }
  if (i == 0) row_ptr[0] = 0;
  sh[t] = nwin;
  __syncthreads();
  for (int off = 1; off < 1024; off <<= 1) {
    int x = (t >= off) ? sh[t - off] : 0;
    __syncthreads();
    sh[t] += x;
    __syncthreads();
  }
  if (i < NA) ntmp[i] = sh[t];
  if (t == 1023) nblk[bid] = sh[1023];
}

// orow[i] = sub-run prefix; orow2[d] = orow[d] - (row_ptr[d]>>2)
__global__ void nscan_p3(const int* __restrict__ ntmp, const int* __restrict__ nblk,
                         const int* __restrict__ row_ptr,
                         int* __restrict__ orow, int* __restrict__ orow2) {
  __shared__ int spre_sh;
  int t = threadIdx.x;
  int bid = blockIdx.x;
  if (t < 64) {
    int v = (t < bid) ? nblk[t] : 0;  // bid <= 48 < 64
    for (int off = 32; off; off >>= 1) v += __shfl_down(v, off);
    if (t == 0) spre_sh = v;
  }
  __syncthreads();
  int spre = spre_sh;
  int i = bid * 1024 + t;
  if (i < NA) {
    orow[i + 1] = ntmp[i] + spre;
    int oi = (t == 0) ? spre : (ntmp[i - 1] + spre);  // orow[i]
    orow2[i] = oi - (row_ptr[i] >> 2);
  }
  if (i == 0) orow[0] = 0;
}

// ---- scat_all: atomic-free scatter via LDS ranks + offset table -----------
__global__ __launch_bounds__(256) void scat_all(
    const int* __restrict__ dst, const int* __restrict__ src,
    const int* __restrict__ row_ptr, const ushort_t* __restrict__ Orel,
    unsigned* __restrict__ ds_pack,
    const int* __restrict__ mol_ids, const int* __restrict__ mrow,
    const unsigned* __restrict__ MH, int* __restrict__ mol_sorted) {
  __shared__ unsigned cnt[RNG];
  __shared__ unsigned mbase[256];
  const int b = blockIdx.x, t = threadIdx.x;
  if (b < NRNG * NCH) {
    const int r = b / NCH, c = b % NCH;
    const int lo = r * RNG;
    for (int i = t; i < RNG; i += 256) cnt[i] = 0;
    __syncthreads();
    const int base = c * CHUNK;
    const ushort_t* Op = Orel + (u64)c * NA;
    for (int k = t; k < CHUNK; k += 256) {
      int e = base + k;
      int d = dst[e];
      unsigned rel = (unsigned)(d - lo);
      if (rel < RNG) {
        unsigned lr = atomicAdd(&cnt[rel], 1u);
        int pos = row_ptr[d] + (int)Op[d] + (int)lr;
        ds_pack[pos] = ((unsigned)d << 16) | (unsigned)src[e];
      }
    }
    return;
  }
  const int c2 = b - NRNG * NCH;  // mol chunk
  if (t < 256) {
    unsigned s = (unsigned)mrow[t];
    for (int cp = 0; cp < c2; cp++) s += MH[cp * 256 + t];
    mbase[t] = s;
    cnt[t] = 0;
  }
  __syncthreads();
  const int base = c2 * CHM;
  for (int k = t; k < CHM; k += 256) {
    int a = base + k;
    int m = mol_ids[a];
    unsigned lr = atomicAdd(&cnt[m], 1u);
    mol_sorted[mbase[m] + lr] = a;
  }
}

// -------- node projection (step 0): states f32 -> PQb fp16 -----------------
__global__ __launch_bounds__(256) void node_proj(
    const float* __restrict__ s_in, const ushort_t* __restrict__ WpB,
    const float* __restrict__ b_in, ushort_t* __restrict__ PQb) {
  const int t = threadIdx.x;
  const int lane = t & 63, wv = t >> 6, quad = lane >> 4, l15 = lane & 15;
  const int n0 = blockIdx.x * 64 + wv * 16;
  int n = n0 + l15; if (n >= NA) n = NA - 1;
  union { half8 v; unsigned d[4]; } a[4];
#pragma unroll
  for (int c = 0; c < 4; c++) {
    const float* p = s_in + (u64)n * 128 + c * 32 + quad * 8;
    float4 f0 = *(const float4*)(p);
    float4 f1 = *(const float4*)(p + 4);
    a[c].d[0] = pkrtz(f0.x, f0.y);
    a[c].d[1] = pkrtz(f0.z, f0.w);
    a[c].d[2] = pkrtz(f1.x, f1.y);
    a[c].d[3] = pkrtz(f1.z, f1.w);
  }
  float binv[4];
#pragma unroll
  for (int nt = 0; nt < 4; nt++) binv[nt] = b_in[nt * 16 + l15];
#pragma unroll
  for (int nt = 0; nt < 8; nt++) {
    f32x4 acc = {0.f, 0.f, 0.f, 0.f};
#pragma unroll
    for (int c = 0; c < 4; c++) {
      half8 b = *(const half8*)&WpB[((nt * 4 + c) * 64 + lane) * 8];
      acc = __builtin_amdgcn_mfma_f32_16x16x32_f16(a[c].v, b, acc, 0, 0, 0);
    }
    float bias = (nt < 4) ? binv[nt] : 0.f;
#pragma unroll
    for (int r = 0; r < 4; r++) {
      int nn = n0 + quad * 4 + r;
      if (nn < NA) PQb[(u64)nn * 128 + nt * 16 + l15] = f2h(acc[r] + bias);
    }
  }
}

// ------ persistent fused edge MLP (fp16 MFMA) -> packed-fp16 sub-run sums --
// 6144 grid waves, each grid-strides over 16-edge tiles with a 3-stage
// software pipeline: pk[t+2] loading | gathers[t+1] loading | compute[t].
__global__ __launch_bounds__(256) void edge_msg(
    const ushort_t* __restrict__ PQb,
    const ushort_t* __restrict__ WhB, const ushort_t* __restrict__ WoB,
    const float* __restrict__ b_h, const float* __restrict__ b_out,
    const unsigned* __restrict__ ds_pack, const int* __restrict__ orow2,
    unsigned* __restrict__ m_buf) {
  __shared__ ushort_t h2s[4][16 * 72];  // per-wave 16 x 64 fp16 repack tile
  const int t = threadIdx.x;
  const int lane = t & 63, wv = t >> 6, quad = lane >> 4, l15 = lane & 15;
  const int gw = blockIdx.x * 4 + wv;   // global wave id in [0, EGW)

  float bh[4], bo[8];
#pragma unroll
  for (int nt = 0; nt < 4; nt++) bh[nt] = b_h[nt * 16 + l15];
#pragma unroll
  for (int nt = 0; nt < 8; nt++) bo[nt] = b_out[nt * 16 + l15];

  ushort_t* hb = h2s[wv];
  const int colq = quad * 8;
  const half2_t z2 = {(_Float16)0.f, (_Float16)0.f};

  struct Ctx {
    int e;            // this lane's edge index (tile*16 + l15)
    unsigned pk;      // (dst<<16)|src
    int o;            // sub-run row of edge e
    ushort8 pv0, pv1, qv0, qv1;
  };

  auto load_pk = [&](Ctx& c, int tile) {
    c.e = tile * 16 + l15;
    c.pk = ds_pack[c.e];
  };
  auto gather = [&](Ctx& c) {
    u64 da = c.pk >> 16, sa = c.pk & 0xffffu;
    c.o = orow2[da] + (c.e >> 2);
    c.pv0 = *(const ushort8*)&PQb[da * 128 + colq];
    c.pv1 = *(const ushort8*)&PQb[da * 128 + 32 + colq];
    c.qv0 = *(const ushort8*)&PQb[sa * 128 + 64 + colq];
    c.qv1 = *(const ushort8*)&PQb[sa * 128 + 96 + colq];
  };
  auto compute = [&](Ctx& c) {
    union UPQ { ushort8 u; half2_t h[4]; };
    UPQ P0, P1, Q0, Q1;
    P0.u = c.pv0; P1.u = c.pv1; Q0.u = c.qv0; Q1.u = c.qv1;
    union { half8 v; half2_t h[4]; } a1[2];
#pragma unroll
    for (int k = 0; k < 4; k++) {
      half2_t s0 = P0.h[k] + Q0.h[k];
      half2_t s1 = P1.h[k] + Q1.h[k];
      a1[0].h[k] = __builtin_elementwise_max(s0, z2);
      a1[1].h[k] = __builtin_elementwise_max(s1, z2);
    }
    // h2 = relu(h1 @ Wh + b_h) -> wave-private LDS repack
#pragma unroll
    for (int nt = 0; nt < 4; nt++) {
      f32x4 acc = {0.f, 0.f, 0.f, 0.f};
#pragma unroll
      for (int cc = 0; cc < 2; cc++) {
        half8 b = *(const half8*)&WhB[((nt * 2 + cc) * 64 + lane) * 8];
        acc = __builtin_amdgcn_mfma_f32_16x16x32_f16(a1[cc].v, b, acc, 0, 0, 0);
      }
#pragma unroll
      for (int r = 0; r < 4; r++)
        hb[(quad * 4 + r) * 72 + nt * 16 + l15] =
            f2h(fmaxf(acc[r] + bh[nt], 0.f));
    }
    half8 a2[2];
    a2[0] = *(const half8*)&hb[l15 * 72 + colq];
    a2[1] = *(const half8*)&hb[l15 * 72 + 32 + colq];
    // m = relu(h2 @ Wout + b_out)
    f32x4 acc2[8];
#pragma unroll
    for (int nt = 0; nt < 8; nt++) {
      f32x4 acc = {0.f, 0.f, 0.f, 0.f};
#pragma unroll
      for (int cc = 0; cc < 2; cc++) {
        half8 b = *(const half8*)&WoB[((nt * 2 + cc) * 64 + lane) * 8];
        acc = __builtin_amdgcn_mfma_f32_16x16x32_f16(a2[cc], b, acc, 0, 0, 0);
      }
      acc2[nt] = acc;
    }
    // segmented sub-run flush over the quad's 4 edges (pks/rows via shfl)
    int pkr[4], orr[4];
#pragma unroll
    for (int r = 0; r < 4; r++) {
      int srcl = (lane & 48) + quad * 4 + r;
      pkr[r] = __shfl((int)c.pk, srcl);
      orr[r] = __shfl(c.o, srcl);
    }
    unsigned prev = ((unsigned)pkr[0]) >> 16;
    int orow_ = orr[0];
    float run[8];
#pragma unroll
    for (int nt = 0; nt < 8; nt++) run[nt] = 0.f;
#pragma unroll
    for (int r = 0; r < 4; r++) {
      unsigned dcur = ((unsigned)pkr[r]) >> 16;
      if (dcur != prev) {
        unsigned* rowp = m_buf + (u64)orow_ * 64;
#pragma unroll
        for (int k = 0; k < 4; k++)
          rowp[k * 16 + l15] = pkrtz(run[2 * k], run[2 * k + 1]);
#pragma unroll
        for (int nt = 0; nt < 8; nt++) run[nt] = 0.f;
        prev = dcur; orow_ = orr[r];
      }
#pragma unroll
      for (int nt = 0; nt < 8; nt++)
        run[nt] += fmaxf(acc2[nt][r] + bo[nt], 0.f);
    }
    unsigned* rowp = m_buf + (u64)orow_ * 64;
#pragma unroll
    for (int k = 0; k < 4; k++)
      rowp[k * 16 + l15] = pkrtz(run[2 * k], run[2 * k + 1]);
  };

  // ---- 3-stage pipelined grid-stride loop ----
  Ctx A, B, C;
  int tc = gw;                 // gw < EGW <= NT always
  load_pk(A, tc);
  int tb = tc + EGW;
  if (tb < NT) load_pk(B, tb);
  gather(A);
  while (tc < NT) {
    int tn = tc + EGW;
    if (tn < NT) gather(B);
    int t2 = tn + EGW;
    if (t2 < NT) load_pk(C, t2);
    compute(A);
    A = B; B = C;
    tc = tn;
  }
}

// ---- fused dst aggregation + projection; bounds staged in LDS -------------
__global__ __launch_bounds__(256) void agg_proj(
    const unsigned* __restrict__ m_buf, const int* __restrict__ orow,
    const ushort_t* __restrict__ WpB, const float* __restrict__ b_in,
    ushort_t* __restrict__ PQb) {
  __shared__ ushort_t a_s[64 * 136];  // 64 rows x 128 fp16, pitch 136
  __shared__ int obs_s[65];
  const int t = threadIdx.x;
  const int lane = t & 63, wv = t >> 6, quad = lane >> 4, l15 = lane & 15;
  const int n0 = blockIdx.x * 64;
  if (t < 65) {
    int idx = n0 + t; if (idx > NA) idx = NA;
    obs_s[t] = orow[idx];
  }
  __syncthreads();

  for (int r = 0; r < 16; r++) {
    const int d = n0 + wv * 16 + r;
    float s0 = 0.f, s1 = 0.f;
    if (d < NA) {
      int ob = obs_s[wv * 16 + r], oe = obs_s[wv * 16 + r + 1];
      int n = oe - ob;
      float t0 = 0.f, t1 = 0.f, u0 = 0.f, u1 = 0.f, v0 = 0.f, v1 = 0.f;
      int full = n & ~3;
      int e = ob;
      for (; e < ob + full; e += 4) {
        unsigned w0 = m_buf[(u64)(e + 0) * 64 + lane];
        unsigned w1 = m_buf[(u64)(e + 1) * 64 + lane];
        unsigned w2 = m_buf[(u64)(e + 2) * 64 + lane];
        unsigned w3 = m_buf[(u64)(e + 3) * 64 + lane];
        s0 += hlo(w0); s1 += hhi(w0);
        t0 += hlo(w1); t1 += hhi(w1);
        u0 += hlo(w2); u1 += hhi(w2);
        v0 += hlo(w3); v1 += hhi(w3);
      }
      int rem = n - full;
      if (rem > 0) {
        int i1 = (rem > 1) ? e + 1 : e;
        int i2 = (rem > 2) ? e + 2 : e;
        unsigned w0 = m_buf[(u64)e * 64 + lane];
        unsigned w1 = m_buf[(u64)i1 * 64 + lane];
        unsigned w2 = m_buf[(u64)i2 * 64 + lane];
        s0 += hlo(w0); s1 += hhi(w0);
        if (rem > 1) { t0 += hlo(w1); t1 += hhi(w1); }
        if (rem > 2) { u0 += hlo(w2); u1 += hhi(w2); }
      }
      s0 = (s0 + t0) + (u0 + v0);
      s1 = (s1 + t1) + (u1 + v1);
    }
    const int row = wv * 16 + r;
    a_s[row * 136 + quad * 32 + l15] = f2h(s0);
    a_s[row * 136 + quad * 32 + 16 + l15] = f2h(s1);
  }
  // wave-private tile: same-wave LDS RAW ordered by lgkmcnt, no barrier

  float binv[4];
#pragma unroll
  for (int nt = 0; nt < 4; nt++) binv[nt] = b_in[nt * 16 + l15];
  half8 a[4];
#pragma unroll
  for (int c = 0; c < 4; c++)
    a[c] = *(const half8*)&a_s[(wv * 16 + l15) * 136 + c * 32 + quad * 8];
#pragma unroll
  for (int nt = 0; nt < 8; nt++) {
    f32x4 acc = {0.f, 0.f, 0.f, 0.f};
#pragma unroll
    for (int c = 0; c < 4; c++) {
      half8 b = *(const half8*)&WpB[((nt * 4 + c) * 64 + lane) * 8];
      acc = __builtin_amdgcn_mfma_f32_16x16x32_f16(a[c], b, acc, 0, 0, 0);
    }
    float bias = (nt < 4) ? binv[nt] : 0.f;
#pragma unroll
    for (int r = 0; r < 4; r++) {
      int nn = n0 + wv * 16 + quad * 4 + r;
      if (nn < NA) PQb[(u64)nn * 128 + nt * 16 + l15] = f2h(acc[r] + bias);
    }
  }
}

// ---- final aggregation: m_buf sub-runs -> per-mol sums; bounds in LDS -----
__global__ __launch_bounds__(256) void agg_mol2(
    const unsigned* __restrict__ m_buf, const int* __restrict__ orow,
    const int* __restrict__ mol_sorted, const int* __restrict__ mol_ids,
    float* __restrict__ mol_repr) {
  __shared__ int mids[64], obs[64], oes[64];
  const int t = threadIdx.x;
  const int lane = t & 63, wv = t >> 6;
  const int base = blockIdx.x * 64;
  if (t < 64) {
    int idx = base + t;
    int r = (idx < NA) ? mol_sorted[idx] : 0;
    mids[t] = (idx < NA) ? mol_ids[r] : -1;
    obs[t] = orow[r];
    oes[t] = orow[r + 1];
  }
  __syncthreads();
  const int c0 = (lane >> 4) * 32 + (lane & 15);  // unpacked cols c0, c0+16
  float r0 = 0.f, r1 = 0.f;
  int prev = mids[wv * 16];
  for (int i = 0; i < 16; i++) {
    int li = wv * 16 + i;
    int m = mids[li];
    if (m != prev) {
      if (prev >= 0) {
        atomicAdd(&mol_repr[(u64)prev * 128 + c0], r0);
        atomicAdd(&mol_repr[(u64)prev * 128 + c0 + 16], r1);
      }
      r0 = 0.f; r1 = 0.f; prev = m;
    }
    if (m >= 0) {
      int ob = obs[li], oe = oes[li];
      int n = oe - ob;
      float t0 = 0.f, t1 = 0.f, u0 = 0.f, u1 = 0.f, v0 = 0.f, v1 = 0.f;
      int full = n & ~3;
      int e = ob;
      for (; e < ob + full; e += 4) {
        unsigned w0 = m_buf[(u64)(e + 0) * 64 + lane];
        unsigned w1 = m_buf[(u64)(e + 1) * 64 + lane];
        unsigned w2 = m_buf[(u64)(e + 2) * 64 + lane];
        unsigned w3 = m_buf[(u64)(e + 3) * 64 + lane];
        r0 += hlo(w0); r1 += hhi(w0);
        t0 += hlo(w1); t1 += hhi(w1);
        u0 += hlo(w2); u1 += hhi(w2);
        v0 += hlo(w3); v1 += hhi(w3);
      }
      int rem = n - full;
      if (rem > 0) {
        int i1 = (rem > 1) ? e + 1 : e;
        int i2 = (rem > 2) ? e + 2 : e;
        unsigned w0 = m_buf[(u64)e * 64 + lane];
        unsigned w1 = m_buf[(u64)i1 * 64 + lane];
        unsigned w2 = m_buf[(u64)i2 * 64 + lane];
        r0 += hlo(w0); r1 += hhi(w0);
        if (rem > 1) { t0 += hlo(w1); t1 += hhi(w1); }
        if (rem > 2) { u0 += hlo(w2); u1 += hhi(w2); }
      }
      r0 += (t0 + u0) + v0;
      r1 += (t1 + u1) + v1;
    }
  }
  if (prev >= 0) {
    atomicAdd(&mol_repr[(u64)prev * 128 + c0], r0);
    atomicAdd(&mol_repr[(u64)prev * 128 + c0 + 16], r1);
  }
}

// ---------------- final tiny MLP per molecule ----------------
__global__ void final_mlp(const float* __restrict__ mol_repr,
                          const float* __restrict__ fc1_w, const float* __restrict__ fc1_b,
                          const float* __restrict__ fc2_w, const float* __restrict__ fc2_b,
                          const float* __restrict__ out_w, const float* __restrict__ out_b,
                          float* __restrict__ out) {
  int m = blockIdx.x, j = threadIdx.x;
  __shared__ float h1sh[64], h2sh[64];
  const float* mr = mol_repr + (u64)m * DF;
  float acc = fc1_b[j];
  for (int d = 0; d < DF; d++) acc = fmaf(mr[d], fc1_w[d * 64 + j], acc);
  h1sh[j] = fmaxf(acc, 0.f);
  __syncthreads();
  acc = fc2_b[j];
  for (int k = 0; k < 64; k++) acc = fmaf(h1sh[k], fc2_w[k * 64 + j], acc);
  h2sh[j] = fmaxf(acc, 0.f);
  __syncthreads();
  if (j < NOUT) {
    acc = out_b[j];
    for (int k = 0; k < 64; k++) acc = fmaf(h2sh[k], out_w[k * NOUT + j], acc);
    out[(u64)m * NOUT + j] = acc;
  }
}

extern "C" void kernel_launch(void* const* d_in, const int* in_sizes, int n_in,
                              void* d_out, int out_size, void* d_ws, size_t ws_size,
                              hipStream_t stream) {
  const float* states = (const float*)d_in[0];
  const float* Win    = (const float*)d_in[1];
  const float* b_in   = (const float*)d_in[2];
  const float* Wh     = (const float*)d_in[3];
  const float* b_h    = (const float*)d_in[4];
  const float* Wout   = (const float*)d_in[5];
  const float* b_out  = (const float*)d_in[6];
  const float* fc1_w  = (const float*)d_in[7];
  const float* fc1_b  = (const float*)d_in[8];
  const float* fc2_w  = (const float*)d_in[9];
  const float* fc2_b  = (const float*)d_in[10];
  const float* out_w  = (const float*)d_in[11];
  const float* out_b  = (const float*)d_in[12];
  const int* src      = (const int*)d_in[13];
  const int* dst      = (const int*)d_in[14];
  const int* mol_ids  = (const int*)d_in[15];

  char* ws = (char*)d_ws;
  u64 o = 0;
  auto alloc = [&](u64 bytes) {
    void* p = ws + o;
    o += (bytes + 255) & ~255ull;
    return p;
  };
  unsigned* m_buf = (unsigned*)alloc((u64)MBUF_ROWS * 64 * 4);
  ushort_t* PQb  = (ushort_t*)alloc((u64)NA * DF * 2);
  ushort_t* WpB  = (ushort_t*)alloc(3 * 16384 * 2);
  ushort_t* WhB  = (ushort_t*)alloc(3 * 4096 * 2);
  ushort_t* WoB  = (ushort_t*)alloc(3 * 8192 * 2);
  // zero-init block (single memset)
  char* zbase    = ws + o;
  float* molr    = (float*)alloc((u64)NMOL * DF * 4);
  int* mcnt      = (int*)alloc(NMOL * 4);
  u64 zbytes     = (u64)((ws + o) - zbase);
  int* counts    = (int*)alloc((u64)NA * 4);
  int* row_ptr   = (int*)alloc((u64)(NA + 1) * 4);
  int* mrow      = (int*)alloc((NMOL + 1) * 4);
  unsigned* ds_pack = (unsigned*)alloc((u64)NE * 4);
  int* mol_sorted = (int*)alloc((u64)NA * 4);
  int* scan_tmp  = (int*)alloc((u64)NA * 4);
  int* blk_sums  = (int*)alloc(64 * 4);
  int* ntmp      = (int*)alloc((u64)NA * 4);
  int* nblk      = (int*)alloc(64 * 4);
  int* orow      = (int*)alloc((u64)(NA + 1) * 4);
  int* orow2     = (int*)alloc((u64)NA * 4);
  ushort_t* H    = (ushort_t*)alloc((u64)NRNG * NCH * RNG * 2);
  ushort_t* Orel = (ushort_t*)alloc((u64)NCH * NA * 2);
  unsigned* MH   = (unsigned*)alloc((u64)NCHM * 256 * 4);
  (void)ws_size; (void)in_sizes; (void)n_in; (void)out_size;

  const int NSCAN = (NA + 1023) / 1024;   // 49

  hipMemsetAsync(zbase, 0, zbytes, stream);

  hist_all<<<HISTB, 256, 0, stream>>>(dst, mol_ids, Win, Wh, Wout,
                                      WpB, WhB, WoB, H, MH, mcnt);
  col_scan<<<(NA + 255) / 256, 256, 0, stream>>>(H, Orel, counts);
  scan_phase1<<<NSCAN, 1024, 0, stream>>>(counts, scan_tmp, blk_sums, mcnt, mrow);
  scan_phase3<<<NSCAN, 1024, 0, stream>>>(scan_tmp, blk_sums, row_ptr, ntmp, nblk);
  nscan_p3<<<NSCAN, 1024, 0, stream>>>(ntmp, nblk, row_ptr, orow, orow2);
  scat_all<<<SCATB, 256, 0, stream>>>(dst, src, row_ptr, Orel, ds_pack,
                                      mol_ids, mrow, MH, mol_sorted);

  node_proj<<<NPB, 256, 0, stream>>>(states, WpB, b_in, PQb);
  for (int t = 0; t < NSTEP; t++) {
    edge_msg<<<EBLK, 256, 0, stream>>>(
        PQb, WhB + t * 4096, WoB + t * 8192,
        b_h + t * 64, b_out + t * 128, ds_pack, orow2, m_buf);
    if (t < NSTEP - 1) {
      agg_proj<<<(NA + 63) / 64, 256, 0, stream>>>(m_buf, orow,
                                                   WpB + (t + 1) * 16384,
                                                   b_in + (t + 1) * 64, PQb);
    } else {
      agg_mol2<<<(NA + 63) / 64, 256, 0, stream>>>(m_buf, orow, mol_sorted,
                                                   mol_ids, molr);
    }
  }
  final_mlp<<<NMOL, 64, 0, stream>>>(molr, fc1_w, fc1_b, fc2_w, fc2_b, out_w, out_b,
                                     (float*)d_out);
}

// Round 10
// 283.088 us; speedup vs baseline: 1.3261x; 1.0228x over previous
//
#include <hip/hip_runtime.h>

typedef unsigned long long u64;
typedef unsigned short ushort_t;

#define NA 50000
#define NE 400000
#define DF 128
#define HID 64
#define NMOL 256
#define NOUT 32
#define NSTEP 3
#define NPB 782  // node_proj blocks: ceil(NA/64)

// ---- atomic-free sort geometry ----
#define RNG 8192          // dst bins per range slice
#define NRNG 7            // ceil(NA/RNG)
#define NCH 64            // edge chunks
#define CHUNK 6250        // NE/NCH
#define NCHM 16           // mol chunks
#define CHM 3125          // NA/NCHM
#define NWB 336           // weight-pack blocks: 86016/256
#define HISTB (NRNG*NCH + NCHM + NWB)   // 800
#define SCATB (NRNG*NCH + NCHM)         // 464
#define MBUF_ROWS 160000  // 4-edge windows: R <= NE/4 + NA = 150000 (+margin)

// ---- persistent edge_msg geometry ----
#define NT (NE / 16)      // 25000 tiles of 16 edges
#define EBLK 1024         // persistent blocks (R6-verified best)
#define EGW (EBLK * 4)    // 4096 grid waves

#define NSCAN 49          // mega_scan blocks: ceil(NA/1024); all co-resident

typedef __attribute__((ext_vector_type(8))) unsigned short ushort8;
typedef __attribute__((ext_vector_type(4))) float f32x4;
typedef __attribute__((ext_vector_type(8))) _Float16 half8;
typedef __attribute__((ext_vector_type(2))) _Float16 half2_t;
typedef __attribute__((ext_vector_type(2))) __fp16 fp16x2;

static __device__ __forceinline__ ushort_t f2h(float f) {
  union { _Float16 h; ushort_t u; } v; v.h = (_Float16)f; return v.u;
}
static __device__ __forceinline__ float hlo(unsigned d) {
  union { unsigned u; half2_t h; } v; v.u = d; return (float)v.h[0];
}
static __device__ __forceinline__ float hhi(unsigned d) {
  union { unsigned u; half2_t h; } v; v.u = d; return (float)v.h[1];
}
static __device__ __forceinline__ unsigned pkrtz(float a, float b) {
  union { fp16x2 h; unsigned u; } v;
  v.h = __builtin_amdgcn_cvt_pkrtz(a, b);
  return v.u;
}

// ---- hist_all: dst-range histograms + mol histograms + weight pack --------
__global__ __launch_bounds__(256) void hist_all(
    const int* __restrict__ dst, const int* __restrict__ mol_ids,
    const float* __restrict__ Win, const float* __restrict__ Wh,
    const float* __restrict__ Wout,
    ushort_t* __restrict__ WpB, ushort_t* __restrict__ WhB,
    ushort_t* __restrict__ WoB,
    ushort_t* __restrict__ H, unsigned* __restrict__ MH,
    int* __restrict__ mcnt) {
  __shared__ unsigned hist[RNG];
  const int b = blockIdx.x, t = threadIdx.x;
  if (b < NRNG * NCH) {
    const int r = b / NCH, c = b % NCH;
    const int lo = r * RNG;
    for (int i = t; i < RNG; i += 256) hist[i] = 0;
    __syncthreads();
    const int base = c * CHUNK;
    for (int k = t; k < CHUNK; k += 256) {
      int d = dst[base + k];
      unsigned rel = (unsigned)(d - lo);
      if (rel < RNG) atomicAdd(&hist[rel], 1u);
    }
    __syncthreads();
    ushort_t* Hp = H + (u64)b * RNG;
    for (int i = t; i < RNG; i += 256) Hp[i] = (ushort_t)hist[i];
    return;
  }
  int b2 = b - NRNG * NCH;
  if (b2 < NCHM) {
    if (t < 256) hist[t] = 0;
    __syncthreads();
    const int base = b2 * CHM;
    for (int k = t; k < CHM; k += 256) atomicAdd(&hist[mol_ids[base + k]], 1u);
    __syncthreads();
    if (t < 256) {
      MH[b2 * 256 + t] = hist[t];
      if (hist[t]) atomicAdd(&mcnt[t], (int)hist[t]);
    }
    return;
  }
  // ---- weight pack (fp16 B-frag order) ----
  int g = (b2 - NCHM) * 256 + t;
  if (g < 3 * 16384) {
    int tt = g / 16384, r = g % 16384;
    int j = r & 7, lane = (r >> 3) & 63, f = r >> 9;
    int kc = f & 3, nt = f >> 2;
    int k = kc * 32 + (lane >> 4) * 8 + j;
    int n = nt * 16 + (lane & 15);
    float v = (n < 64) ? Win[tt * 16384 + k * 64 + n]
                       : Win[tt * 16384 + (128 + k) * 64 + (n - 64)];
    WpB[g] = f2h(v);
  }
  int g2 = g - 3 * 16384;
  if (g2 >= 0 && g2 < 3 * 4096) {
    int tt = g2 / 4096, r = g2 % 4096;
    int j = r & 7, lane = (r >> 3) & 63, f = r >> 9;
    int kc = f & 1, nt = f >> 1;
    int k = kc * 32 + (lane >> 4) * 8 + j;
    int n = nt * 16 + (lane & 15);
    WhB[g2] = f2h(Wh[tt * 4096 + k * 64 + n]);
  }
  int g3 = g2 - 3 * 4096;
  if (g3 >= 0 && g3 < 3 * 8192) {
    int tt = g3 / 8192, r = g3 % 8192;
    int j = r & 7, lane = (r >> 3) & 63, f = r >> 9;
    int kc = f & 1, nt = f >> 1;
    int k = kc * 32 + (lane >> 4) * 8 + j;
    int n = nt * 16 + (lane & 15);
    WoB[g3] = f2h(Wout[tt * 8192 + k * 128 + n]);
  }
}

// ---- mega_scan: col_scan + counts-scan + nwin-scan + mol-scan, one kernel -
// 49 blocks, all co-resident; cross-block prefix via publish(sum+1)+spin.
__global__ __launch_bounds__(1024) void mega_scan(
    const ushort_t* __restrict__ H, ushort_t* __restrict__ Orel,
    int* __restrict__ row_ptr, int* __restrict__ orow, int* __restrict__ orow2,
    const int* __restrict__ mcnt, int* __restrict__ mrow,
    int* __restrict__ stA, int* __restrict__ stB) {
  __shared__ int sh[1024];
  __shared__ int pre_sh;
  const int t = threadIdx.x, bid = blockIdx.x;
  const int i = bid * 1024 + t;

  // phase A: per-bin count over chunks (col_scan) + Orel table
  int cnt = 0;
  if (i < NA) {
    int r = i >> 13, ii = i & (RNG - 1);
    const ushort_t* Hp = H + ((u64)r * NCH) * RNG + ii;
    unsigned acc = 0;
    for (int c = 0; c < NCH; c++) {
      Orel[(u64)c * NA + i] = (ushort_t)acc;
      acc += Hp[(u64)c * RNG];
    }
    cnt = (int)acc;
  }

  // phase B: block inclusive scan of cnt
  sh[t] = cnt;
  __syncthreads();
  for (int off = 1; off < 1024; off <<= 1) {
    int x = (t >= off) ? sh[t - off] : 0;
    __syncthreads();
    sh[t] += x;
    __syncthreads();
  }
  const int incl = sh[t];
  if (t == 0) atomicExch(&stA[bid], sh[1023] + 1);  // publish aggregate(+1)
  if (t < 64) {
    int v = 0;
    if (t < bid) {                       // bid <= 48 < 64
      do { v = atomicAdd(&stA[t], 0); } while (v == 0);
      v -= 1;
    }
    for (int off = 32; off; off >>= 1) v += __shfl_down(v, off);
    if (t == 0) pre_sh = v;
  }
  __syncthreads();
  const int excl1 = pre_sh;

  int rs = 0, nwin = 0;
  if (i < NA) {
    int re = excl1 + incl;
    rs = re - cnt;
    row_ptr[i + 1] = re;
    if (re > rs) nwin = ((re - 1) >> 2) - (rs >> 2) + 1;
  }
  if (i == 0) row_ptr[0] = 0;
  __syncthreads();

  // phase C: block inclusive scan of nwin
  sh[t] = nwin;
  __syncthreads();
  for (int off = 1; off < 1024; off <<= 1) {
    int x = (t >= off) ? sh[t - off] : 0;
    __syncthreads();
    sh[t] += x;
    __syncthreads();
  }
  const int incl2 = sh[t];
  if (t == 0) atomicExch(&stB[bid], sh[1023] + 1);
  if (t < 64) {
    int v = 0;
    if (t < bid) {
      do { v = atomicAdd(&stB[t], 0); } while (v == 0);
      v -= 1;
    }
    for (int off = 32; off; off >>= 1) v += __shfl_down(v, off);
    if (t == 0) pre_sh = v;
  }
  __syncthreads();
  const int excl2 = pre_sh;
  if (i < NA) {
    orow[i + 1] = excl2 + incl2;
    orow2[i] = (excl2 + incl2 - nwin) - (rs >> 2);
  }
  if (i == 0) orow[0] = 0;

  // mol-histogram scan in last block (mcnt ready: hist_all precedes)
  if (bid == NSCAN - 1) {
    __syncthreads();
    sh[t] = (t < NMOL) ? mcnt[t] : 0;
    __syncthreads();
    for (int off = 1; off < NMOL; off <<= 1) {
      int x = (t >= off && t < NMOL) ? sh[t - off] : 0;
      __syncthreads();
      if (t < NMOL) sh[t] += x;
      __syncthreads();
    }
    if (t < NMOL) mrow[t + 1] = sh[t];
    if (t == 0) mrow[0] = 0;
  }
}

// ---- scat_all: atomic-free scatter via LDS ranks + offset table -----------
__global__ __launch_bounds__(256) void scat_all(
    const int* __restrict__ dst, const int* __restrict__ src,
    const int* __restrict__ row_ptr, const ushort_t* __restrict__ Orel,
    unsigned* __restrict__ ds_pack,
    const int* __restrict__ mol_ids, const int* __restrict__ mrow,
    const unsigned* __restrict__ MH, int* __restrict__ mol_sorted) {
  __shared__ unsigned cnt[RNG];
  __shared__ unsigned mbase[256];
  const int b = blockIdx.x, t = threadIdx.x;
  if (b < NRNG * NCH) {
    const int r = b / NCH, c = b % NCH;
    const int lo = r * RNG;
    for (int i = t; i < RNG; i += 256) cnt[i] = 0;
    __syncthreads();
    const int base = c * CHUNK;
    const ushort_t* Op = Orel + (u64)c * NA;
    for (int k = t; k < CHUNK; k += 256) {
      int e = base + k;
      int d = dst[e];
      unsigned rel = (unsigned)(d - lo);
      if (rel < RNG) {
        unsigned lr = atomicAdd(&cnt[rel], 1u);
        int pos = row_ptr[d] + (int)Op[d] + (int)lr;
        ds_pack[pos] = ((unsigned)d << 16) | (unsigned)src[e];
      }
    }
    return;
  }
  const int c2 = b - NRNG * NCH;  // mol chunk
  if (t < 256) {
    unsigned s = (unsigned)mrow[t];
    for (int cp = 0; cp < c2; cp++) s += MH[cp * 256 + t];
    mbase[t] = s;
    cnt[t] = 0;
  }
  __syncthreads();
  const int base = c2 * CHM;
  for (int k = t; k < CHM; k += 256) {
    int a = base + k;
    int m = mol_ids[a];
    unsigned lr = atomicAdd(&cnt[m], 1u);
    mol_sorted[mbase[m] + lr] = a;
  }
}

// -------- node projection (step 0): states f32 -> PQb fp16 -----------------
__global__ __launch_bounds__(256) void node_proj(
    const float* __restrict__ s_in, const ushort_t* __restrict__ WpB,
    const float* __restrict__ b_in, ushort_t* __restrict__ PQb) {
  const int t = threadIdx.x;
  const int lane = t & 63, wv = t >> 6, quad = lane >> 4, l15 = lane & 15;
  const int n0 = blockIdx.x * 64 + wv * 16;
  int n = n0 + l15; if (n >= NA) n = NA - 1;
  union { half8 v; unsigned d[4]; } a[4];
#pragma unroll
  for (int c = 0; c < 4; c++) {
    const float* p = s_in + (u64)n * 128 + c * 32 + quad * 8;
    float4 f0 = *(const float4*)(p);
    float4 f1 = *(const float4*)(p + 4);
    a[c].d[0] = pkrtz(f0.x, f0.y);
    a[c].d[1] = pkrtz(f0.z, f0.w);
    a[c].d[2] = pkrtz(f1.x, f1.y);
    a[c].d[3] = pkrtz(f1.z, f1.w);
  }
  float binv[4];
#pragma unroll
  for (int nt = 0; nt < 4; nt++) binv[nt] = b_in[nt * 16 + l15];
#pragma unroll
  for (int nt = 0; nt < 8; nt++) {
    f32x4 acc = {0.f, 0.f, 0.f, 0.f};
#pragma unroll
    for (int c = 0; c < 4; c++) {
      half8 b = *(const half8*)&WpB[((nt * 4 + c) * 64 + lane) * 8];
      acc = __builtin_amdgcn_mfma_f32_16x16x32_f16(a[c].v, b, acc, 0, 0, 0);
    }
    float bias = (nt < 4) ? binv[nt] : 0.f;
#pragma unroll
    for (int r = 0; r < 4; r++) {
      int nn = n0 + quad * 4 + r;
      if (nn < NA) PQb[(u64)nn * 128 + nt * 16 + l15] = f2h(acc[r] + bias);
    }
  }
}

// ------ persistent fused edge MLP (fp16 MFMA) -> packed-fp16 sub-run sums --
// 4096 grid waves, each grid-strides over 16-edge tiles with a 3-stage
// software pipeline: pk[t+2] loading | gathers[t+1] loading | compute[t].
__global__ __launch_bounds__(256) void edge_msg(
    const ushort_t* __restrict__ PQb,
    const ushort_t* __restrict__ WhB, const ushort_t* __restrict__ WoB,
    const float* __restrict__ b_h, const float* __restrict__ b_out,
    const unsigned* __restrict__ ds_pack, const int* __restrict__ orow2,
    unsigned* __restrict__ m_buf) {
  __shared__ ushort_t h2s[4][16 * 72];  // per-wave 16 x 64 fp16 repack tile
  const int t = threadIdx.x;
  const int lane = t & 63, wv = t >> 6, quad = lane >> 4, l15 = lane & 15;
  const int gw = blockIdx.x * 4 + wv;   // global wave id in [0, EGW)

  float bh[4], bo[8];
#pragma unroll
  for (int nt = 0; nt < 4; nt++) bh[nt] = b_h[nt * 16 + l15];
#pragma unroll
  for (int nt = 0; nt < 8; nt++) bo[nt] = b_out[nt * 16 + l15];

  ushort_t* hb = h2s[wv];
  const int colq = quad * 8;
  const half2_t z2 = {(_Float16)0.f, (_Float16)0.f};

  struct Ctx {
    int e;            // this lane's edge index (tile*16 + l15)
    unsigned pk;      // (dst<<16)|src
    int o;            // sub-run row of edge e
    ushort8 pv0, pv1, qv0, qv1;
  };

  auto load_pk = [&](Ctx& c, int tile) {
    c.e = tile * 16 + l15;
    c.pk = ds_pack[c.e];
  };
  auto gather = [&](Ctx& c) {
    u64 da = c.pk >> 16, sa = c.pk & 0xffffu;
    c.o = orow2[da] + (c.e >> 2);
    c.pv0 = *(const ushort8*)&PQb[da * 128 + colq];
    c.pv1 = *(const ushort8*)&PQb[da * 128 + 32 + colq];
    c.qv0 = *(const ushort8*)&PQb[sa * 128 + 64 + colq];
    c.qv1 = *(const ushort8*)&PQb[sa * 128 + 96 + colq];
  };
  auto compute = [&](Ctx& c) {
    union UPQ { ushort8 u; half2_t h[4]; };
    UPQ P0, P1, Q0, Q1;
    P0.u = c.pv0; P1.u = c.pv1; Q0.u = c.qv0; Q1.u = c.qv1;
    union { half8 v; half2_t h[4]; } a1[2];
#pragma unroll
    for (int k = 0; k < 4; k++) {
      half2_t s0 = P0.h[k] + Q0.h[k];
      half2_t s1 = P1.h[k] + Q1.h[k];
      a1[0].h[k] = __builtin_elementwise_max(s0, z2);
      a1[1].h[k] = __builtin_elementwise_max(s1, z2);
    }
    // h2 = relu(h1 @ Wh + b_h) -> wave-private LDS repack
#pragma unroll
    for (int nt = 0; nt < 4; nt++) {
      f32x4 acc = {0.f, 0.f, 0.f, 0.f};
#pragma unroll
      for (int cc = 0; cc < 2; cc++) {
        half8 b = *(const half8*)&WhB[((nt * 2 + cc) * 64 + lane) * 8];
        acc = __builtin_amdgcn_mfma_f32_16x16x32_f16(a1[cc].v, b, acc, 0, 0, 0);
      }
#pragma unroll
      for (int r = 0; r < 4; r++)
        hb[(quad * 4 + r) * 72 + nt * 16 + l15] =
            f2h(fmaxf(acc[r] + bh[nt], 0.f));
    }
    half8 a2[2];
    a2[0] = *(const half8*)&hb[l15 * 72 + colq];
    a2[1] = *(const half8*)&hb[l15 * 72 + 32 + colq];
    // m = relu(h2 @ Wout + b_out)
    f32x4 acc2[8];
#pragma unroll
    for (int nt = 0; nt < 8; nt++) {
      f32x4 acc = {0.f, 0.f, 0.f, 0.f};
#pragma unroll
      for (int cc = 0; cc < 2; cc++) {
        half8 b = *(const half8*)&WoB[((nt * 2 + cc) * 64 + lane) * 8];
        acc = __builtin_amdgcn_mfma_f32_16x16x32_f16(a2[cc], b, acc, 0, 0, 0);
      }
      acc2[nt] = acc;
    }
    // segmented sub-run flush over the quad's 4 edges (pks/rows via shfl)
    int pkr[4], orr[4];
#pragma unroll
    for (int r = 0; r < 4; r++) {
      int srcl = (lane & 48) + quad * 4 + r;
      pkr[r] = __shfl((int)c.pk, srcl);
      orr[r] = __shfl(c.o, srcl);
    }
    unsigned prev = ((unsigned)pkr[0]) >> 16;
    int orow_ = orr[0];
    float run[8];
#pragma unroll
    for (int nt = 0; nt < 8; nt++) run[nt] = 0.f;
#pragma unroll
    for (int r = 0; r < 4; r++) {
      unsigned dcur = ((unsigned)pkr[r]) >> 16;
      if (dcur != prev) {
        unsigned* rowp = m_buf + (u64)orow_ * 64;
#pragma unroll
        for (int k = 0; k < 4; k++)
          rowp[k * 16 + l15] = pkrtz(run[2 * k], run[2 * k + 1]);
#pragma unroll
        for (int nt = 0; nt < 8; nt++) run[nt] = 0.f;
        prev = dcur; orow_ = orr[r];
      }
#pragma unroll
      for (int nt = 0; nt < 8; nt++)
        run[nt] += fmaxf(acc2[nt][r] + bo[nt], 0.f);
    }
    unsigned* rowp = m_buf + (u64)orow_ * 64;
#pragma unroll
    for (int k = 0; k < 4; k++)
      rowp[k * 16 + l15] = pkrtz(run[2 * k], run[2 * k + 1]);
  };

  // ---- 3-stage pipelined grid-stride loop ----
  Ctx A, B, C;
  int tc = gw;                 // gw < EGW <= NT always
  load_pk(A, tc);
  int tb = tc + EGW;
  if (tb < NT) load_pk(B, tb);
  gather(A);
  while (tc < NT) {
    int tn = tc + EGW;
    if (tn < NT) gather(B);
    int t2 = tn + EGW;
    if (t2 < NT) load_pk(C, t2);
    compute(A);
    A = B; B = C;
    tc = tn;
  }
}

// ---- fused dst aggregation + projection; bounds staged in LDS -------------
__global__ __launch_bounds__(256) void agg_proj(
    const unsigned* __restrict__ m_buf, const int* __restrict__ orow,
    const ushort_t* __restrict__ WpB, const float* __restrict__ b_in,
    ushort_t* __restrict__ PQb) {
  __shared__ ushort_t a_s[64 * 136];  // 64 rows x 128 fp16, pitch 136
  __shared__ int obs_s[65];
  const int t = threadIdx.x;
  const int lane = t & 63, wv = t >> 6, quad = lane >> 4, l15 = lane & 15;
  const int n0 = blockIdx.x * 64;
  if (t < 65) {
    int idx = n0 + t; if (idx > NA) idx = NA;
    obs_s[t] = orow[idx];
  }
  __syncthreads();

  for (int r = 0; r < 16; r++) {
    const int d = n0 + wv * 16 + r;
    float s0 = 0.f, s1 = 0.f;
    if (d < NA) {
      int ob = obs_s[wv * 16 + r], oe = obs_s[wv * 16 + r + 1];
      int n = oe - ob;
      float t0 = 0.f, t1 = 0.f, u0 = 0.f, u1 = 0.f, v0 = 0.f, v1 = 0.f;
      int full = n & ~3;
      int e = ob;
      for (; e < ob + full; e += 4) {
        unsigned w0 = m_buf[(u64)(e + 0) * 64 + lane];
        unsigned w1 = m_buf[(u64)(e + 1) * 64 + lane];
        unsigned w2 = m_buf[(u64)(e + 2) * 64 + lane];
        unsigned w3 = m_buf[(u64)(e + 3) * 64 + lane];
        s0 += hlo(w0); s1 += hhi(w0);
        t0 += hlo(w1); t1 += hhi(w1);
        u0 += hlo(w2); u1 += hhi(w2);
        v0 += hlo(w3); v1 += hhi(w3);
      }
      int rem = n - full;
      if (rem > 0) {
        int i1 = (rem > 1) ? e + 1 : e;
        int i2 = (rem > 2) ? e + 2 : e;
        unsigned w0 = m_buf[(u64)e * 64 + lane];
        unsigned w1 = m_buf[(u64)i1 * 64 + lane];
        unsigned w2 = m_buf[(u64)i2 * 64 + lane];
        s0 += hlo(w0); s1 += hhi(w0);
        if (rem > 1) { t0 += hlo(w1); t1 += hhi(w1); }
        if (rem > 2) { u0 += hlo(w2); u1 += hhi(w2); }
      }
      s0 = (s0 + t0) + (u0 + v0);
      s1 = (s1 + t1) + (u1 + v1);
    }
    const int row = wv * 16 + r;
    a_s[row * 136 + quad * 32 + l15] = f2h(s0);
    a_s[row * 136 + quad * 32 + 16 + l15] = f2h(s1);
  }
  // wave-private tile: same-wave LDS RAW ordered by lgkmcnt, no barrier

  float binv[4];
#pragma unroll
  for (int nt = 0; nt < 4; nt++) binv[nt] = b_in[nt * 16 + l15];
  half8 a[4];
#pragma unroll
  for (int c = 0; c < 4; c++)
    a[c] = *(const half8*)&a_s[(wv * 16 + l15) * 136 + c * 32 + quad * 8];
#pragma unroll
  for (int nt = 0; nt < 8; nt++) {
    f32x4 acc = {0.f, 0.f, 0.f, 0.f};
#pragma unroll
    for (int c = 0; c < 4; c++) {
      half8 b = *(const half8*)&WpB[((nt * 4 + c) * 64 + lane) * 8];
      acc = __builtin_amdgcn_mfma_f32_16x16x32_f16(a[c], b, acc, 0, 0, 0);
    }
    float bias = (nt < 4) ? binv[nt] : 0.f;
#pragma unroll
    for (int r = 0; r < 4; r++) {
      int nn = n0 + wv * 16 + quad * 4 + r;
      if (nn < NA) PQb[(u64)nn * 128 + nt * 16 + l15] = f2h(acc[r] + bias);
    }
  }
}

// ---- final aggregation: m_buf sub-runs -> per-mol sums; bounds in LDS -----
__global__ __launch_bounds__(256) void agg_mol2(
    const unsigned* __restrict__ m_buf, const int* __restrict__ orow,
    const int* __restrict__ mol_sorted, const int* __restrict__ mol_ids,
    float* __restrict__ mol_repr) {
  __shared__ int mids[64], obs[64], oes[64];
  const int t = threadIdx.x;
  const int lane = t & 63, wv = t >> 6;
  const int base = blockIdx.x * 64;
  if (t < 64) {
    int idx = base + t;
    int r = (idx < NA) ? mol_sorted[idx] : 0;
    mids[t] = (idx < NA) ? mol_ids[r] : -1;
    obs[t] = orow[r];
    oes[t] = orow[r + 1];
  }
  __syncthreads();
  const int c0 = (lane >> 4) * 32 + (lane & 15);  // unpacked cols c0, c0+16
  float r0 = 0.f, r1 = 0.f;
  int prev = mids[wv * 16];
  for (int i = 0; i < 16; i++) {
    int li = wv * 16 + i;
    int m = mids[li];
    if (m != prev) {
      if (prev >= 0) {
        atomicAdd(&mol_repr[(u64)prev * 128 + c0], r0);
        atomicAdd(&mol_repr[(u64)prev * 128 + c0 + 16], r1);
      }
      r0 = 0.f; r1 = 0.f; prev = m;
    }
    if (m >= 0) {
      int ob = obs[li], oe = oes[li];
      int n = oe - ob;
      float t0 = 0.f, t1 = 0.f, u0 = 0.f, u1 = 0.f, v0 = 0.f, v1 = 0.f;
      int full = n & ~3;
      int e = ob;
      for (; e < ob + full; e += 4) {
        unsigned w0 = m_buf[(u64)(e + 0) * 64 + lane];
        unsigned w1 = m_buf[(u64)(e + 1) * 64 + lane];
        unsigned w2 = m_buf[(u64)(e + 2) * 64 + lane];
        unsigned w3 = m_buf[(u64)(e + 3) * 64 + lane];
        r0 += hlo(w0); r1 += hhi(w0);
        t0 += hlo(w1); t1 += hhi(w1);
        u0 += hlo(w2); u1 += hhi(w2);
        v0 += hlo(w3); v1 += hhi(w3);
      }
      int rem = n - full;
      if (rem > 0) {
        int i1 = (rem > 1) ? e + 1 : e;
        int i2 = (rem > 2) ? e + 2 : e;
        unsigned w0 = m_buf[(u64)e * 64 + lane];
        unsigned w1 = m_buf[(u64)i1 * 64 + lane];
        unsigned w2 = m_buf[(u64)i2 * 64 + lane];
        r0 += hlo(w0); r1 += hhi(w0);
        if (rem > 1) { t0 += hlo(w1); t1 += hhi(w1); }
        if (rem > 2) { u0 += hlo(w2); u1 += hhi(w2); }
      }
      r0 += (t0 + u0) + v0;
      r1 += (t1 + u1) + v1;
    }
  }
  if (prev >= 0) {
    atomicAdd(&mol_repr[(u64)prev * 128 + c0], r0);
    atomicAdd(&mol_repr[(u64)prev * 128 + c0 + 16], r1);
  }
}

// ---------------- final tiny MLP per molecule ----------------
__global__ void final_mlp(const float* __restrict__ mol_repr,
                          const float* __restrict__ fc1_w, const float* __restrict__ fc1_b,
                          const float* __restrict__ fc2_w, const float* __restrict__ fc2_b,
                          const float* __restrict__ out_w, const float* __restrict__ out_b,
                          float* __restrict__ out) {
  int m = blockIdx.x, j = threadIdx.x;
  __shared__ float h1sh[64], h2sh[64];
  const float* mr = mol_repr + (u64)m * DF;
  float acc = fc1_b[j];
  for (int d = 0; d < DF; d++) acc = fmaf(mr[d], fc1_w[d * 64 + j], acc);
  h1sh[j] = fmaxf(acc, 0.f);
  __syncthreads();
  acc = fc2_b[j];
  for (int k = 0; k < 64; k++) acc = fmaf(h1sh[k], fc2_w[k * 64 + j], acc);
  h2sh[j] = fmaxf(acc, 0.f);
  __syncthreads();
  if (j < NOUT) {
    acc = out_b[j];
    for (int k = 0; k < 64; k++) acc = fmaf(h2sh[k], out_w[k * NOUT + j], acc);
    out[(u64)m * NOUT + j] = acc;
  }
}

extern "C" void kernel_launch(void* const* d_in, const int* in_sizes, int n_in,
                              void* d_out, int out_size, void* d_ws, size_t ws_size,
                              hipStream_t stream) {
  const float* states = (const float*)d_in[0];
  const float* Win    = (const float*)d_in[1];
  const float* b_in   = (const float*)d_in[2];
  const float* Wh     = (const float*)d_in[3];
  const float* b_h    = (const float*)d_in[4];
  const float* Wout   = (const float*)d_in[5];
  const float* b_out  = (const float*)d_in[6];
  const float* fc1_w  = (const float*)d_in[7];
  const float* fc1_b  = (const float*)d_in[8];
  const float* fc2_w  = (const float*)d_in[9];
  const float* fc2_b  = (const float*)d_in[10];
  const float* out_w  = (const float*)d_in[11];
  const float* out_b  = (const float*)d_in[12];
  const int* src      = (const int*)d_in[13];
  const int* dst      = (const int*)d_in[14];
  const int* mol_ids  = (const int*)d_in[15];

  char* ws = (char*)d_ws;
  u64 o = 0;
  auto alloc = [&](u64 bytes) {
    void* p = ws + o;
    o += (bytes + 255) & ~255ull;
    return p;
  };
  unsigned* m_buf = (unsigned*)alloc((u64)MBUF_ROWS * 64 * 4);
  ushort_t* PQb  = (ushort_t*)alloc((u64)NA * DF * 2);
  ushort_t* WpB  = (ushort_t*)alloc(3 * 16384 * 2);
  ushort_t* WhB  = (ushort_t*)alloc(3 * 4096 * 2);
  ushort_t* WoB  = (ushort_t*)alloc(3 * 8192 * 2);
  // zero-init block (single memset)
  char* zbase    = ws + o;
  float* molr    = (float*)alloc((u64)NMOL * DF * 4);
  int* mcnt      = (int*)alloc(NMOL * 4);
  int* stA       = (int*)alloc(64 * 4);
  int* stB       = (int*)alloc(64 * 4);
  u64 zbytes     = (u64)((ws + o) - zbase);
  int* row_ptr   = (int*)alloc((u64)(NA + 1) * 4);
  int* mrow      = (int*)alloc((NMOL + 1) * 4);
  unsigned* ds_pack = (unsigned*)alloc((u64)NE * 4);
  int* mol_sorted = (int*)alloc((u64)NA * 4);
  int* orow      = (int*)alloc((u64)(NA + 1) * 4);
  int* orow2     = (int*)alloc((u64)NA * 4);
  ushort_t* H    = (ushort_t*)alloc((u64)NRNG * NCH * RNG * 2);
  ushort_t* Orel = (ushort_t*)alloc((u64)NCH * NA * 2);
  unsigned* MH   = (unsigned*)alloc((u64)NCHM * 256 * 4);
  (void)ws_size; (void)in_sizes; (void)n_in; (void)out_size;

  hipMemsetAsync(zbase, 0, zbytes, stream);

  hist_all<<<HISTB, 256, 0, stream>>>(dst, mol_ids, Win, Wh, Wout,
                                      WpB, WhB, WoB, H, MH, mcnt);
  mega_scan<<<NSCAN, 1024, 0, stream>>>(H, Orel, row_ptr, orow, orow2,
                                        mcnt, mrow, stA, stB);
  scat_all<<<SCATB, 256, 0, stream>>>(dst, src, row_ptr, Orel, ds_pack,
                                      mol_ids, mrow, MH, mol_sorted);

  node_proj<<<NPB, 256, 0, stream>>>(states, WpB, b_in, PQb);
  for (int t = 0; t < NSTEP; t++) {
    edge_msg<<<EBLK, 256, 0, stream>>>(
        PQb, WhB + t * 4096, WoB + t * 8192,
        b_h + t * 64, b_out + t * 128, ds_pack, orow2, m_buf);
    if (t < NSTEP - 1) {
      agg_proj<<<(NA + 63) / 64, 256, 0, stream>>>(m_buf, orow,
                                                   WpB + (t + 1) * 16384,
                                                   b_in + (t + 1) * 64, PQb);
    } else {
      agg_mol2<<<(NA + 63) / 64, 256, 0, stream>>>(m_buf, orow, mol_sorted,
                                                   mol_ids, molr);
    }
  }
  final_mlp<<<NMOL, 64, 0, stream>>>(molr, fc1_w, fc1_b, fc2_w, fc2_b, out_w, out_b,
                                     (float*)d_out);
}

// Round 11
// 276.446 us; speedup vs baseline: 1.3580x; 1.0240x over previous
//
#include <hip/hip_runtime.h>

typedef unsigned long long u64;
typedef unsigned short ushort_t;

#define NA 50000
#define NE 400000
#define DF 128
#define HID 64
#define NMOL 256
#define NOUT 32
#define NSTEP 3
#define NPB 782  // node_proj blocks: ceil(NA/64)

// ---- atomic-free sort geometry ----
#define RNG 8192          // dst bins per range slice
#define NRNG 7            // ceil(NA/RNG)
#define NCH 64            // edge chunks
#define CHUNK 6250        // NE/NCH
#define NCHM 16           // mol chunks
#define CHM 3125          // NA/NCHM
#define NWB 336           // weight-pack blocks: 86016/256
#define HISTB (NRNG*NCH + NCHM + NWB)   // 800
#define SCATB (NRNG*NCH + NCHM)         // 464
#define MBUF_ROWS 160000  // 4-edge windows: R <= NE/4 + NA = 150000 (+margin)

// ---- persistent edge_msg geometry ----
#define NT (NE / 16)      // 25000 tiles of 16 edges
#define EBLK 1024         // persistent blocks (R6/R10-verified best)
#define EGW (EBLK * 4)    // 4096 grid waves

#define NSCAN 49          // mega_scan blocks: ceil(NA/1024); all co-resident

typedef __attribute__((ext_vector_type(8))) unsigned short ushort8;
typedef __attribute__((ext_vector_type(4))) float f32x4;
typedef __attribute__((ext_vector_type(8))) _Float16 half8;
typedef __attribute__((ext_vector_type(2))) _Float16 half2_t;
typedef __attribute__((ext_vector_type(2))) __fp16 fp16x2;

static __device__ __forceinline__ ushort_t f2h(float f) {
  union { _Float16 h; ushort_t u; } v; v.h = (_Float16)f; return v.u;
}
static __device__ __forceinline__ float hlo(unsigned d) {
  union { unsigned u; half2_t h; } v; v.u = d; return (float)v.h[0];
}
static __device__ __forceinline__ float hhi(unsigned d) {
  union { unsigned u; half2_t h; } v; v.u = d; return (float)v.h[1];
}
static __device__ __forceinline__ unsigned pkrtz(float a, float b) {
  union { fp16x2 h; unsigned u; } v;
  v.h = __builtin_amdgcn_cvt_pkrtz(a, b);
  return v.u;
}

// ---- hist_all: dst-range histograms + mol histograms + weight pack --------
__global__ __launch_bounds__(256) void hist_all(
    const int* __restrict__ dst, const int* __restrict__ mol_ids,
    const float* __restrict__ Win, const float* __restrict__ Wh,
    const float* __restrict__ Wout,
    ushort_t* __restrict__ WpB, ushort_t* __restrict__ WhB,
    ushort_t* __restrict__ WoB,
    ushort_t* __restrict__ H, unsigned* __restrict__ MH,
    int* __restrict__ mcnt) {
  __shared__ unsigned hist[RNG];
  const int b = blockIdx.x, t = threadIdx.x;
  if (b < NRNG * NCH) {
    const int r = b / NCH, c = b % NCH;
    const int lo = r * RNG;
    for (int i = t; i < RNG; i += 256) hist[i] = 0;
    __syncthreads();
    const int base = c * CHUNK;
    for (int k = t; k < CHUNK; k += 256) {
      int d = dst[base + k];
      unsigned rel = (unsigned)(d - lo);
      if (rel < RNG) atomicAdd(&hist[rel], 1u);
    }
    __syncthreads();
    ushort_t* Hp = H + (u64)b * RNG;
    for (int i = t; i < RNG; i += 256) Hp[i] = (ushort_t)hist[i];
    return;
  }
  int b2 = b - NRNG * NCH;
  if (b2 < NCHM) {
    if (t < 256) hist[t] = 0;
    __syncthreads();
    const int base = b2 * CHM;
    for (int k = t; k < CHM; k += 256) atomicAdd(&hist[mol_ids[base + k]], 1u);
    __syncthreads();
    if (t < 256) {
      MH[b2 * 256 + t] = hist[t];
      if (hist[t]) atomicAdd(&mcnt[t], (int)hist[t]);
    }
    return;
  }
  // ---- weight pack (fp16 B-frag order) ----
  int g = (b2 - NCHM) * 256 + t;
  if (g < 3 * 16384) {
    int tt = g / 16384, r = g % 16384;
    int j = r & 7, lane = (r >> 3) & 63, f = r >> 9;
    int kc = f & 3, nt = f >> 2;
    int k = kc * 32 + (lane >> 4) * 8 + j;
    int n = nt * 16 + (lane & 15);
    float v = (n < 64) ? Win[tt * 16384 + k * 64 + n]
                       : Win[tt * 16384 + (128 + k) * 64 + (n - 64)];
    WpB[g] = f2h(v);
  }
  int g2 = g - 3 * 16384;
  if (g2 >= 0 && g2 < 3 * 4096) {
    int tt = g2 / 4096, r = g2 % 4096;
    int j = r & 7, lane = (r >> 3) & 63, f = r >> 9;
    int kc = f & 1, nt = f >> 1;
    int k = kc * 32 + (lane >> 4) * 8 + j;
    int n = nt * 16 + (lane & 15);
    WhB[g2] = f2h(Wh[tt * 4096 + k * 64 + n]);
  }
  int g3 = g2 - 3 * 4096;
  if (g3 >= 0 && g3 < 3 * 8192) {
    int tt = g3 / 8192, r = g3 % 8192;
    int j = r & 7, lane = (r >> 3) & 63, f = r >> 9;
    int kc = f & 1, nt = f >> 1;
    int k = kc * 32 + (lane >> 4) * 8 + j;
    int n = nt * 16 + (lane & 15);
    WoB[g3] = f2h(Wout[tt * 8192 + k * 128 + n]);
  }
}

// ---- mega_scan: col_scan + counts-scan + nwin-scan + mol-scan, one kernel -
// 49 blocks, all co-resident; cross-block prefix via publish(sum+1)+spin.
__global__ __launch_bounds__(1024) void mega_scan(
    const ushort_t* __restrict__ H, ushort_t* __restrict__ Orel,
    int* __restrict__ row_ptr, int* __restrict__ orow, int* __restrict__ orow2,
    const int* __restrict__ mcnt, int* __restrict__ mrow,
    int* __restrict__ stA, int* __restrict__ stB) {
  __shared__ int sh[1024];
  __shared__ int pre_sh;
  const int t = threadIdx.x, bid = blockIdx.x;
  const int i = bid * 1024 + t;

  // phase A: per-bin count over chunks (col_scan) + Orel table
  int cnt = 0;
  if (i < NA) {
    int r = i >> 13, ii = i & (RNG - 1);
    const ushort_t* Hp = H + ((u64)r * NCH) * RNG + ii;
    unsigned acc = 0;
    for (int c = 0; c < NCH; c++) {
      Orel[(u64)c * NA + i] = (ushort_t)acc;
      acc += Hp[(u64)c * RNG];
    }
    cnt = (int)acc;
  }

  // phase B: block inclusive scan of cnt
  sh[t] = cnt;
  __syncthreads();
  for (int off = 1; off < 1024; off <<= 1) {
    int x = (t >= off) ? sh[t - off] : 0;
    __syncthreads();
    sh[t] += x;
    __syncthreads();
  }
  const int incl = sh[t];
  if (t == 0) atomicExch(&stA[bid], sh[1023] + 1);  // publish aggregate(+1)
  if (t < 64) {
    int v = 0;
    if (t < bid) {                       // bid <= 48 < 64
      do { v = atomicAdd(&stA[t], 0); } while (v == 0);
      v -= 1;
    }
    for (int off = 32; off; off >>= 1) v += __shfl_down(v, off);
    if (t == 0) pre_sh = v;
  }
  __syncthreads();
  const int excl1 = pre_sh;

  int rs = 0, nwin = 0;
  if (i < NA) {
    int re = excl1 + incl;
    rs = re - cnt;
    row_ptr[i + 1] = re;
    if (re > rs) nwin = ((re - 1) >> 2) - (rs >> 2) + 1;
  }
  if (i == 0) row_ptr[0] = 0;
  __syncthreads();

  // phase C: block inclusive scan of nwin
  sh[t] = nwin;
  __syncthreads();
  for (int off = 1; off < 1024; off <<= 1) {
    int x = (t >= off) ? sh[t - off] : 0;
    __syncthreads();
    sh[t] += x;
    __syncthreads();
  }
  const int incl2 = sh[t];
  if (t == 0) atomicExch(&stB[bid], sh[1023] + 1);
  if (t < 64) {
    int v = 0;
    if (t < bid) {
      do { v = atomicAdd(&stB[t], 0); } while (v == 0);
      v -= 1;
    }
    for (int off = 32; off; off >>= 1) v += __shfl_down(v, off);
    if (t == 0) pre_sh = v;
  }
  __syncthreads();
  const int excl2 = pre_sh;
  if (i < NA) {
    orow[i + 1] = excl2 + incl2;
    orow2[i] = (excl2 + incl2 - nwin) - (rs >> 2);
  }
  if (i == 0) orow[0] = 0;

  // mol-histogram scan in last block (mcnt ready: hist_all precedes)
  if (bid == NSCAN - 1) {
    __syncthreads();
    sh[t] = (t < NMOL) ? mcnt[t] : 0;
    __syncthreads();
    for (int off = 1; off < NMOL; off <<= 1) {
      int x = (t >= off && t < NMOL) ? sh[t - off] : 0;
      __syncthreads();
      if (t < NMOL) sh[t] += x;
      __syncthreads();
    }
    if (t < NMOL) mrow[t + 1] = sh[t];
    if (t == 0) mrow[0] = 0;
  }
}

// ---- scat_node: scatter (blocks < SCATB) + node projection (rest) ---------
// Both depend only on prior kernels; fused so node_proj overlaps the scatter.
__global__ __launch_bounds__(256) void scat_node(
    const int* __restrict__ dst, const int* __restrict__ src,
    const int* __restrict__ row_ptr, const ushort_t* __restrict__ Orel,
    unsigned* __restrict__ ds_pack,
    const int* __restrict__ mol_ids, const int* __restrict__ mrow,
    const unsigned* __restrict__ MH, int* __restrict__ mol_sorted,
    const float* __restrict__ s_in, const ushort_t* __restrict__ WpB,
    const float* __restrict__ b_in, ushort_t* __restrict__ PQb) {
  __shared__ unsigned cnt[RNG];
  __shared__ unsigned mbase[256];
  const int b = blockIdx.x, t = threadIdx.x;
  if (b < NRNG * NCH) {
    const int r = b / NCH, c = b % NCH;
    const int lo = r * RNG;
    for (int i = t; i < RNG; i += 256) cnt[i] = 0;
    __syncthreads();
    const int base = c * CHUNK;
    const ushort_t* Op = Orel + (u64)c * NA;
    for (int k = t; k < CHUNK; k += 256) {
      int e = base + k;
      int d = dst[e];
      unsigned rel = (unsigned)(d - lo);
      if (rel < RNG) {
        unsigned lr = atomicAdd(&cnt[rel], 1u);
        int pos = row_ptr[d] + (int)Op[d] + (int)lr;
        ds_pack[pos] = ((unsigned)d << 16) | (unsigned)src[e];
      }
    }
    return;
  }
  if (b < SCATB) {
    const int c2 = b - NRNG * NCH;  // mol chunk
    if (t < 256) {
      unsigned s = (unsigned)mrow[t];
      for (int cp = 0; cp < c2; cp++) s += MH[cp * 256 + t];
      mbase[t] = s;
      cnt[t] = 0;
    }
    __syncthreads();
    const int base = c2 * CHM;
    for (int k = t; k < CHM; k += 256) {
      int a = base + k;
      int m = mol_ids[a];
      unsigned lr = atomicAdd(&cnt[m], 1u);
      mol_sorted[mbase[m] + lr] = a;
    }
    return;
  }
  // ---- node projection (step 0): states f32 -> PQb fp16 ----
  const int nb = b - SCATB;
  const int lane = t & 63, wv = t >> 6, quad = lane >> 4, l15 = lane & 15;
  const int n0 = nb * 64 + wv * 16;
  int n = n0 + l15; if (n >= NA) n = NA - 1;
  union { half8 v; unsigned d[4]; } a[4];
#pragma unroll
  for (int c = 0; c < 4; c++) {
    const float* p = s_in + (u64)n * 128 + c * 32 + quad * 8;
    float4 f0 = *(const float4*)(p);
    float4 f1 = *(const float4*)(p + 4);
    a[c].d[0] = pkrtz(f0.x, f0.y);
    a[c].d[1] = pkrtz(f0.z, f0.w);
    a[c].d[2] = pkrtz(f1.x, f1.y);
    a[c].d[3] = pkrtz(f1.z, f1.w);
  }
  float binv[4];
#pragma unroll
  for (int nt = 0; nt < 4; nt++) binv[nt] = b_in[nt * 16 + l15];
#pragma unroll
  for (int nt = 0; nt < 8; nt++) {
    f32x4 acc = {0.f, 0.f, 0.f, 0.f};
#pragma unroll
    for (int c = 0; c < 4; c++) {
      half8 bb = *(const half8*)&WpB[((nt * 4 + c) * 64 + lane) * 8];
      acc = __builtin_amdgcn_mfma_f32_16x16x32_f16(a[c].v, bb, acc, 0, 0, 0);
    }
    float bias = (nt < 4) ? binv[nt] : 0.f;
#pragma unroll
    for (int r = 0; r < 4; r++) {
      int nn = n0 + quad * 4 + r;
      if (nn < NA) PQb[(u64)nn * 128 + nt * 16 + l15] = f2h(acc[r] + bias);
    }
  }
}

// ------ persistent fused edge MLP (fp16 MFMA) -> packed-fp16 sub-run sums --
// 4096 grid waves, each grid-strides over 16-edge tiles with a 3-stage
// software pipeline: pk[t+2] loading | gathers[t+1] loading | compute[t].
__global__ __launch_bounds__(256) void edge_msg(
    const ushort_t* __restrict__ PQb,
    const ushort_t* __restrict__ WhB, const ushort_t* __restrict__ WoB,
    const float* __restrict__ b_h, const float* __restrict__ b_out,
    const unsigned* __restrict__ ds_pack, const int* __restrict__ orow2,
    unsigned* __restrict__ m_buf) {
  __shared__ ushort_t h2s[4][16 * 72];  // per-wave 16 x 64 fp16 repack tile
  const int t = threadIdx.x;
  const int lane = t & 63, wv = t >> 6, quad = lane >> 4, l15 = lane & 15;
  const int gw = blockIdx.x * 4 + wv;   // global wave id in [0, EGW)

  float bh[4], bo[8];
#pragma unroll
  for (int nt = 0; nt < 4; nt++) bh[nt] = b_h[nt * 16 + l15];
#pragma unroll
  for (int nt = 0; nt < 8; nt++) bo[nt] = b_out[nt * 16 + l15];

  ushort_t* hb = h2s[wv];
  const int colq = quad * 8;
  const half2_t z2 = {(_Float16)0.f, (_Float16)0.f};

  struct Ctx {
    int e;            // this lane's edge index (tile*16 + l15)
    unsigned pk;      // (dst<<16)|src
    int o;            // sub-run row of edge e
    ushort8 pv0, pv1, qv0, qv1;
  };

  auto load_pk = [&](Ctx& c, int tile) {
    c.e = tile * 16 + l15;
    c.pk = ds_pack[c.e];
  };
  auto gather = [&](Ctx& c) {
    u64 da = c.pk >> 16, sa = c.pk & 0xffffu;
    c.o = orow2[da] + (c.e >> 2);
    c.pv0 = *(const ushort8*)&PQb[da * 128 + colq];
    c.pv1 = *(const ushort8*)&PQb[da * 128 + 32 + colq];
    c.qv0 = *(const ushort8*)&PQb[sa * 128 + 64 + colq];
    c.qv1 = *(const ushort8*)&PQb[sa * 128 + 96 + colq];
  };
  auto compute = [&](Ctx& c) {
    union UPQ { ushort8 u; half2_t h[4]; };
    UPQ P0, P1, Q0, Q1;
    P0.u = c.pv0; P1.u = c.pv1; Q0.u = c.qv0; Q1.u = c.qv1;
    union { half8 v; half2_t h[4]; } a1[2];
#pragma unroll
    for (int k = 0; k < 4; k++) {
      half2_t s0 = P0.h[k] + Q0.h[k];
      half2_t s1 = P1.h[k] + Q1.h[k];
      a1[0].h[k] = __builtin_elementwise_max(s0, z2);
      a1[1].h[k] = __builtin_elementwise_max(s1, z2);
    }
    // h2 = relu(h1 @ Wh + b_h) -> wave-private LDS repack
#pragma unroll
    for (int nt = 0; nt < 4; nt++) {
      f32x4 acc = {0.f, 0.f, 0.f, 0.f};
#pragma unroll
      for (int cc = 0; cc < 2; cc++) {
        half8 b = *(const half8*)&WhB[((nt * 2 + cc) * 64 + lane) * 8];
        acc = __builtin_amdgcn_mfma_f32_16x16x32_f16(a1[cc].v, b, acc, 0, 0, 0);
      }
#pragma unroll
      for (int r = 0; r < 4; r++)
        hb[(quad * 4 + r) * 72 + nt * 16 + l15] =
            f2h(fmaxf(acc[r] + bh[nt], 0.f));
    }
    half8 a2[2];
    a2[0] = *(const half8*)&hb[l15 * 72 + colq];
    a2[1] = *(const half8*)&hb[l15 * 72 + 32 + colq];
    // m = relu(h2 @ Wout + b_out)
    f32x4 acc2[8];
#pragma unroll
    for (int nt = 0; nt < 8; nt++) {
      f32x4 acc = {0.f, 0.f, 0.f, 0.f};
#pragma unroll
      for (int cc = 0; cc < 2; cc++) {
        half8 b = *(const half8*)&WoB[((nt * 2 + cc) * 64 + lane) * 8];
        acc = __builtin_amdgcn_mfma_f32_16x16x32_f16(a2[cc], b, acc, 0, 0, 0);
      }
      acc2[nt] = acc;
    }
    // segmented sub-run flush over the quad's 4 edges (pks/rows via shfl)
    int pkr[4], orr[4];
#pragma unroll
    for (int r = 0; r < 4; r++) {
      int srcl = (lane & 48) + quad * 4 + r;
      pkr[r] = __shfl((int)c.pk, srcl);
      orr[r] = __shfl(c.o, srcl);
    }
    unsigned prev = ((unsigned)pkr[0]) >> 16;
    int orow_ = orr[0];
    float run[8];
#pragma unroll
    for (int nt = 0; nt < 8; nt++) run[nt] = 0.f;
#pragma unroll
    for (int r = 0; r < 4; r++) {
      unsigned dcur = ((unsigned)pkr[r]) >> 16;
      if (dcur != prev) {
        unsigned* rowp = m_buf + (u64)orow_ * 64;
#pragma unroll
        for (int k = 0; k < 4; k++)
          rowp[k * 16 + l15] = pkrtz(run[2 * k], run[2 * k + 1]);
#pragma unroll
        for (int nt = 0; nt < 8; nt++) run[nt] = 0.f;
        prev = dcur; orow_ = orr[r];
      }
#pragma unroll
      for (int nt = 0; nt < 8; nt++)
        run[nt] += fmaxf(acc2[nt][r] + bo[nt], 0.f);
    }
    unsigned* rowp = m_buf + (u64)orow_ * 64;
#pragma unroll
    for (int k = 0; k < 4; k++)
      rowp[k * 16 + l15] = pkrtz(run[2 * k], run[2 * k + 1]);
  };

  // ---- 3-stage pipelined grid-stride loop ----
  Ctx A, B, C;
  int tc = gw;                 // gw < EGW <= NT always
  load_pk(A, tc);
  int tb = tc + EGW;
  if (tb < NT) load_pk(B, tb);
  gather(A);
  while (tc < NT) {
    int tn = tc + EGW;
    if (tn < NT) gather(B);
    int t2 = tn + EGW;
    if (t2 < NT) load_pk(C, t2);
    compute(A);
    A = B; B = C;
    tc = tn;
  }
}

// ---- fused dst aggregation + projection; bounds staged in LDS -------------
__global__ __launch_bounds__(256) void agg_proj(
    const unsigned* __restrict__ m_buf, const int* __restrict__ orow,
    const ushort_t* __restrict__ WpB, const float* __restrict__ b_in,
    ushort_t* __restrict__ PQb) {
  __shared__ ushort_t a_s[64 * 136];  // 64 rows x 128 fp16, pitch 136
  __shared__ int obs_s[65];
  const int t = threadIdx.x;
  const int lane = t & 63, wv = t >> 6, quad = lane >> 4, l15 = lane & 15;
  const int n0 = blockIdx.x * 64;
  if (t < 65) {
    int idx = n0 + t; if (idx > NA) idx = NA;
    obs_s[t] = orow[idx];
  }
  __syncthreads();

  for (int r = 0; r < 16; r++) {
    const int d = n0 + wv * 16 + r;
    float s0 = 0.f, s1 = 0.f;
    if (d < NA) {
      int ob = obs_s[wv * 16 + r], oe = obs_s[wv * 16 + r + 1];
      int n = oe - ob;
      float t0 = 0.f, t1 = 0.f, u0 = 0.f, u1 = 0.f, v0 = 0.f, v1 = 0.f;
      int full = n & ~3;
      int e = ob;
      for (; e < ob + full; e += 4) {
        unsigned w0 = m_buf[(u64)(e + 0) * 64 + lane];
        unsigned w1 = m_buf[(u64)(e + 1) * 64 + lane];
        unsigned w2 = m_buf[(u64)(e + 2) * 64 + lane];
        unsigned w3 = m_buf[(u64)(e + 3) * 64 + lane];
        s0 += hlo(w0); s1 += hhi(w0);
        t0 += hlo(w1); t1 += hhi(w1);
        u0 += hlo(w2); u1 += hhi(w2);
        v0 += hlo(w3); v1 += hhi(w3);
      }
      int rem = n - full;
      if (rem > 0) {
        int i1 = (rem > 1) ? e + 1 : e;
        int i2 = (rem > 2) ? e + 2 : e;
        unsigned w0 = m_buf[(u64)e * 64 + lane];
        unsigned w1 = m_buf[(u64)i1 * 64 + lane];
        unsigned w2 = m_buf[(u64)i2 * 64 + lane];
        s0 += hlo(w0); s1 += hhi(w0);
        if (rem > 1) { t0 += hlo(w1); t1 += hhi(w1); }
        if (rem > 2) { u0 += hlo(w2); u1 += hhi(w2); }
      }
      s0 = (s0 + t0) + (u0 + v0);
      s1 = (s1 + t1) + (u1 + v1);
    }
    const int row = wv * 16 + r;
    a_s[row * 136 + quad * 32 + l15] = f2h(s0);
    a_s[row * 136 + quad * 32 + 16 + l15] = f2h(s1);
  }
  // wave-private tile: same-wave LDS RAW ordered by lgkmcnt, no barrier

  float binv[4];
#pragma unroll
  for (int nt = 0; nt < 4; nt++) binv[nt] = b_in[nt * 16 + l15];
  half8 a[4];
#pragma unroll
  for (int c = 0; c < 4; c++)
    a[c] = *(const half8*)&a_s[(wv * 16 + l15) * 136 + c * 32 + quad * 8];
#pragma unroll
  for (int nt = 0; nt < 8; nt++) {
    f32x4 acc = {0.f, 0.f, 0.f, 0.f};
#pragma unroll
    for (int c = 0; c < 4; c++) {
      half8 b = *(const half8*)&WpB[((nt * 4 + c) * 64 + lane) * 8];
      acc = __builtin_amdgcn_mfma_f32_16x16x32_f16(a[c], b, acc, 0, 0, 0);
    }
    float bias = (nt < 4) ? binv[nt] : 0.f;
#pragma unroll
    for (int r = 0; r < 4; r++) {
      int nn = n0 + wv * 16 + quad * 4 + r;
      if (nn < NA) PQb[(u64)nn * 128 + nt * 16 + l15] = f2h(acc[r] + bias);
    }
  }
}

// ---- final aggregation: m_buf sub-runs -> per-mol sums; bounds in LDS -----
__global__ __launch_bounds__(256) void agg_mol2(
    const unsigned* __restrict__ m_buf, const int* __restrict__ orow,
    const int* __restrict__ mol_sorted, const int* __restrict__ mol_ids,
    float* __restrict__ mol_repr) {
  __shared__ int mids[64], obs[64], oes[64];
  const int t = threadIdx.x;
  const int lane = t & 63, wv = t >> 6;
  const int base = blockIdx.x * 64;
  if (t < 64) {
    int idx = base + t;
    int r = (idx < NA) ? mol_sorted[idx] : 0;
    mids[t] = (idx < NA) ? mol_ids[r] : -1;
    obs[t] = orow[r];
    oes[t] = orow[r + 1];
  }
  __syncthreads();
  const int c0 = (lane >> 4) * 32 + (lane & 15);  // unpacked cols c0, c0+16
  float r0 = 0.f, r1 = 0.f;
  int prev = mids[wv * 16];
  for (int i = 0; i < 16; i++) {
    int li = wv * 16 + i;
    int m = mids[li];
    if (m != prev) {
      if (prev >= 0) {
        atomicAdd(&mol_repr[(u64)prev * 128 + c0], r0);
        atomicAdd(&mol_repr[(u64)prev * 128 + c0 + 16], r1);
      }
      r0 = 0.f; r1 = 0.f; prev = m;
    }
    if (m >= 0) {
      int ob = obs[li], oe = oes[li];
      int n = oe - ob;
      float t0 = 0.f, t1 = 0.f, u0 = 0.f, u1 = 0.f, v0 = 0.f, v1 = 0.f;
      int full = n & ~3;
      int e = ob;
      for (; e < ob + full; e += 4) {
        unsigned w0 = m_buf[(u64)(e + 0) * 64 + lane];
        unsigned w1 = m_buf[(u64)(e + 1) * 64 + lane];
        unsigned w2 = m_buf[(u64)(e + 2) * 64 + lane];
        unsigned w3 = m_buf[(u64)(e + 3) * 64 + lane];
        r0 += hlo(w0); r1 += hhi(w0);
        t0 += hlo(w1); t1 += hhi(w1);
        u0 += hlo(w2); u1 += hhi(w2);
        v0 += hlo(w3); v1 += hhi(w3);
      }
      int rem = n - full;
      if (rem > 0) {
        int i1 = (rem > 1) ? e + 1 : e;
        int i2 = (rem > 2) ? e + 2 : e;
        unsigned w0 = m_buf[(u64)e * 64 + lane];
        unsigned w1 = m_buf[(u64)i1 * 64 + lane];
        unsigned w2 = m_buf[(u64)i2 * 64 + lane];
        r0 += hlo(w0); r1 += hhi(w0);
        if (rem > 1) { t0 += hlo(w1); t1 += hhi(w1); }
        if (rem > 2) { u0 += hlo(w2); u1 += hhi(w2); }
      }
      r0 += (t0 + u0) + v0;
      r1 += (t1 + u1) + v1;
    }
  }
  if (prev >= 0) {
    atomicAdd(&mol_repr[(u64)prev * 128 + c0], r0);
    atomicAdd(&mol_repr[(u64)prev * 128 + c0 + 16], r1);
  }
}

// ---------------- final tiny MLP per molecule ----------------
__global__ void final_mlp(const float* __restrict__ mol_repr,
                          const float* __restrict__ fc1_w, const float* __restrict__ fc1_b,
                          const float* __restrict__ fc2_w, const float* __restrict__ fc2_b,
                          const float* __restrict__ out_w, const float* __restrict__ out_b,
                          float* __restrict__ out) {
  int m = blockIdx.x, j = threadIdx.x;
  __shared__ float h1sh[64], h2sh[64];
  const float* mr = mol_repr + (u64)m * DF;
  float acc = fc1_b[j];
  for (int d = 0; d < DF; d++) acc = fmaf(mr[d], fc1_w[d * 64 + j], acc);
  h1sh[j] = fmaxf(acc, 0.f);
  __syncthreads();
  acc = fc2_b[j];
  for (int k = 0; k < 64; k++) acc = fmaf(h1sh[k], fc2_w[k * 64 + j], acc);
  h2sh[j] = fmaxf(acc, 0.f);
  __syncthreads();
  if (j < NOUT) {
    acc = out_b[j];
    for (int k = 0; k < 64; k++) acc = fmaf(h2sh[k], out_w[k * NOUT + j], acc);
    out[(u64)m * NOUT + j] = acc;
  }
}

extern "C" void kernel_launch(void* const* d_in, const int* in_sizes, int n_in,
                              void* d_out, int out_size, void* d_ws, size_t ws_size,
                              hipStream_t stream) {
  const float* states = (const float*)d_in[0];
  const float* Win    = (const float*)d_in[1];
  const float* b_in   = (const float*)d_in[2];
  const float* Wh     = (const float*)d_in[3];
  const float* b_h    = (const float*)d_in[4];
  const float* Wout   = (const float*)d_in[5];
  const float* b_out  = (const float*)d_in[6];
  const float* fc1_w  = (const float*)d_in[7];
  const float* fc1_b  = (const float*)d_in[8];
  const float* fc2_w  = (const float*)d_in[9];
  const float* fc2_b  = (const float*)d_in[10];
  const float* out_w  = (const float*)d_in[11];
  const float* out_b  = (const float*)d_in[12];
  const int* src      = (const int*)d_in[13];
  const int* dst      = (const int*)d_in[14];
  const int* mol_ids  = (const int*)d_in[15];

  char* ws = (char*)d_ws;
  u64 o = 0;
  auto alloc = [&](u64 bytes) {
    void* p = ws + o;
    o += (bytes + 255) & ~255ull;
    return p;
  };
  unsigned* m_buf = (unsigned*)alloc((u64)MBUF_ROWS * 64 * 4);
  ushort_t* PQb  = (ushort_t*)alloc((u64)NA * DF * 2);
  ushort_t* WpB  = (ushort_t*)alloc(3 * 16384 * 2);
  ushort_t* WhB  = (ushort_t*)alloc(3 * 4096 * 2);
  ushort_t* WoB  = (ushort_t*)alloc(3 * 8192 * 2);
  // zero-init block (single memset)
  char* zbase    = ws + o;
  float* molr    = (float*)alloc((u64)NMOL * DF * 4);
  int* mcnt      = (int*)alloc(NMOL * 4);
  int* stA       = (int*)alloc(64 * 4);
  int* stB       = (int*)alloc(64 * 4);
  u64 zbytes     = (u64)((ws + o) - zbase);
  int* row_ptr   = (int*)alloc((u64)(NA + 1) * 4);
  int* mrow      = (int*)alloc((NMOL + 1) * 4);
  unsigned* ds_pack = (unsigned*)alloc((u64)NE * 4);
  int* mol_sorted = (int*)alloc((u64)NA * 4);
  int* orow      = (int*)alloc((u64)(NA + 1) * 4);
  int* orow2     = (int*)alloc((u64)NA * 4);
  ushort_t* H    = (ushort_t*)alloc((u64)NRNG * NCH * RNG * 2);
  ushort_t* Orel = (ushort_t*)alloc((u64)NCH * NA * 2);
  unsigned* MH   = (unsigned*)alloc((u64)NCHM * 256 * 4);
  (void)ws_size; (void)in_sizes; (void)n_in; (void)out_size;

  hipMemsetAsync(zbase, 0, zbytes, stream);

  hist_all<<<HISTB, 256, 0, stream>>>(dst, mol_ids, Win, Wh, Wout,
                                      WpB, WhB, WoB, H, MH, mcnt);
  mega_scan<<<NSCAN, 1024, 0, stream>>>(H, Orel, row_ptr, orow, orow2,
                                        mcnt, mrow, stA, stB);
  scat_node<<<SCATB + NPB, 256, 0, stream>>>(dst, src, row_ptr, Orel, ds_pack,
                                             mol_ids, mrow, MH, mol_sorted,
                                             states, WpB, b_in, PQb);
  for (int t = 0; t < NSTEP; t++) {
    edge_msg<<<EBLK, 256, 0, stream>>>(
        PQb, WhB + t * 4096, WoB + t * 8192,
        b_h + t * 64, b_out + t * 128, ds_pack, orow2, m_buf);
    if (t < NSTEP - 1) {
      agg_proj<<<(NA + 63) / 64, 256, 0, stream>>>(m_buf, orow,
                                                   WpB + (t + 1) * 16384,
                                                   b_in + (t + 1) * 64, PQb);
    } else {
      agg_mol2<<<(NA + 63) / 64, 256, 0, stream>>>(m_buf, orow, mol_sorted,
                                                   mol_ids, molr);
    }
  }
  final_mlp<<<NMOL, 64, 0, stream>>>(molr, fc1_w, fc1_b, fc2_w, fc2_b, out_w, out_b,
                                     (float*)d_out);
}